// Round 1
// baseline (2337.771 us; speedup 1.0000x reference)
//
#include <hip/hip_runtime.h>
#include <cstddef>

// ---------------------------------------------------------------- reductions
__device__ __forceinline__ float block_reduce_sum(float v, float* sm) {
#pragma unroll
  for (int off = 32; off > 0; off >>= 1) v += __shfl_down(v, off, 64);
  const int lane = threadIdx.x & 63, wid = threadIdx.x >> 6;
  __syncthreads();               // protect sm reuse across successive calls
  if (lane == 0) sm[wid] = v;
  __syncthreads();
  if (threadIdx.x == 0) {
    float t = 0.f;
    const int nw = (blockDim.x + 63) >> 6;
    for (int i = 0; i < nw; ++i) t += sm[i];
    sm[0] = t;
  }
  __syncthreads();
  return sm[0];
}

// ---------------------------------------------------------------- ternarize
// TWN: delta = 0.7*mean|w|; alpha = mean|w| over entries above delta;
// q = alpha*sign(w)*mask  (forward value of the STE expression)
__global__ void ternarize_kernel(const float* __restrict__ w,
                                 float* __restrict__ q, int n) {
  __shared__ float sm[8];
  float s = 0.f;
  for (int i = threadIdx.x; i < n; i += blockDim.x) s += fabsf(w[i]);
  const float total = block_reduce_sum(s, sm);
  const float delta = 0.7f * total / (float)n;
  float s1 = 0.f, s2 = 0.f;
  for (int i = threadIdx.x; i < n; i += blockDim.x) {
    const float a = fabsf(w[i]);
    if (a > delta) { s1 += 1.f; s2 += a; }
  }
  const float cnt  = block_reduce_sum(s1, sm);
  const float asum = block_reduce_sum(s2, sm);
  const float alpha = asum / fmaxf(cnt, 1.f);
  for (int i = threadIdx.x; i < n; i += blockDim.x) {
    const float wi = w[i];
    q[i] = (fabsf(wi) > delta) ? copysignf(alpha, wi) : 0.f;
  }
}

// ---------------------------------------------------------------- BN fold
__global__ void bnfold_kernel(const float* __restrict__ g,
                              const float* __restrict__ b,
                              const float* __restrict__ m,
                              const float* __restrict__ v,
                              float* __restrict__ scale,
                              float* __restrict__ bias, int n) {
  const int i = blockIdx.x * blockDim.x + threadIdx.x;
  if (i < n) {
    const float inv = g[i] / sqrtf(v[i] + 1e-5f);
    scale[i] = inv;
    bias[i]  = b[i] - m[i] * inv;
  }
}

// ---------------------------------------------------------------- direct conv
// One thread = one output pixel x KB output channels. Weights for the KB
// channels staged in LDS; inner reads are wave-uniform -> LDS broadcast
// (conflict-free). Fused BN + ReLU epilogue. pad=1, kernel 3x3.
template <int CIN, int KB, int STRIDE>
__global__ __launch_bounds__(256) void conv3x3_bn_relu(
    const float* __restrict__ x, const float* __restrict__ q,
    const float* __restrict__ scale, const float* __restrict__ bias,
    float* __restrict__ y, int H, int W, int OH, int OW, int K) {
  __shared__ float wsm[KB * CIN * 9];
  const int oc0 = blockIdx.y * KB;
  for (int i = threadIdx.x; i < KB * CIN * 9; i += blockDim.x)
    wsm[i] = q[(size_t)oc0 * CIN * 9 + i];
  __syncthreads();

  const int HWo = OH * OW;
  const int s = blockIdx.x * blockDim.x + threadIdx.x;
  if (s >= HWo) return;
  const int oh = s / OW, ow = s % OW;

  const float* xn = x + (size_t)blockIdx.z * CIN * H * W;
  float acc[KB];
#pragma unroll
  for (int j = 0; j < KB; ++j) acc[j] = 0.f;

  const int ih0 = oh * STRIDE - 1, iw0 = ow * STRIDE - 1;
  for (int ic = 0; ic < CIN; ++ic) {
    const float* xc = xn + (size_t)ic * H * W;
#pragma unroll
    for (int kh = 0; kh < 3; ++kh) {
      const int ih = ih0 + kh;
      if ((unsigned)ih >= (unsigned)H) continue;
      const float* xr = xc + (size_t)ih * W;
#pragma unroll
      for (int kw = 0; kw < 3; ++kw) {
        const int iw = iw0 + kw;
        const float xv = ((unsigned)iw < (unsigned)W) ? xr[iw] : 0.f;
        const int wi = ic * 9 + kh * 3 + kw;
#pragma unroll
        for (int j = 0; j < KB; ++j) acc[j] += xv * wsm[j * CIN * 9 + wi];
      }
    }
  }

  const size_t ob = ((size_t)blockIdx.z * K + oc0) * (size_t)HWo + s;
#pragma unroll
  for (int j = 0; j < KB; ++j) {
    const float v = acc[j] * scale[oc0 + j] + bias[oc0 + j];
    y[ob + (size_t)j * HWo] = fmaxf(v, 0.f);
  }
}

// ---------------------------------------------------------------- global pool
__global__ void pool_kernel(const float* __restrict__ a,
                            float* __restrict__ pooled, int n0, int Cc,
                            int HW) {
  __shared__ float sm[8];
  const int c = blockIdx.x;
  const float* p = a + ((size_t)blockIdx.y * Cc + c) * (size_t)HW;
  float s = 0.f;
  for (int i = threadIdx.x; i < HW; i += blockDim.x) s += p[i];
  const float t = block_reduce_sum(s, sm);
  if (threadIdx.x == 0)
    pooled[(size_t)(n0 + blockIdx.y) * Cc + c] = t / (float)HW;
}

// ---------------------------------------------------------------- linear
__global__ void linear_kernel(const float* __restrict__ pooled,
                              const float* __restrict__ ql,
                              const float* __restrict__ bl,
                              float* __restrict__ out) {
  const int idx = blockIdx.x * blockDim.x + threadIdx.x;
  if (idx >= 64 * 10) return;
  const int n = idx / 10, o = idx % 10;
  const float* p = pooled + (size_t)n * 128;
  const float* w = ql + (size_t)o * 128;
  float s = 0.f;
#pragma unroll 4
  for (int c = 0; c < 128; ++c) s += p[c] * w[c];
  out[idx] = s + bl[o];
}

// ---------------------------------------------------------------- launch
extern "C" void kernel_launch(void* const* d_in, const int* in_sizes, int n_in,
                              void* d_out, int out_size, void* d_ws,
                              size_t ws_size, hipStream_t stream) {
  const float* x  = (const float*)d_in[0];
  const float* w1 = (const float*)d_in[1];
  const float* g1 = (const float*)d_in[2];
  const float* b1 = (const float*)d_in[3];
  const float* m1 = (const float*)d_in[4];
  const float* v1 = (const float*)d_in[5];
  const float* w2 = (const float*)d_in[6];
  const float* g2 = (const float*)d_in[7];
  const float* b2 = (const float*)d_in[8];
  const float* m2 = (const float*)d_in[9];
  const float* v2 = (const float*)d_in[10];
  const float* w3 = (const float*)d_in[11];
  const float* g3 = (const float*)d_in[12];
  const float* b3 = (const float*)d_in[13];
  const float* m3 = (const float*)d_in[14];
  const float* v3 = (const float*)d_in[15];
  const float* wl = (const float*)d_in[16];
  const float* bl = (const float*)d_in[17];
  float* out = (float*)d_out;

  // ---- workspace layout (floats) ----
  float* Wf = (float*)d_ws;
  float* q1 = Wf;              // 32*3*9    = 864
  float* q2 = q1 + 864;        // 64*32*9   = 18432
  float* q3 = q2 + 18432;      // 128*64*9  = 73728
  float* ql = q3 + 73728;      // 10*128    = 1280
  float* s1 = ql + 1280;  float* bb1 = s1 + 32;
  float* s2 = bb1 + 32;   float* bb2 = s2 + 64;
  float* s3 = bb2 + 64;   float* bb3 = s3 + 128;
  float* pooled = bb3 + 128;   // 64*128    = 8192
  float* actbase = pooled + 8192;
  const size_t fixedf = (size_t)(actbase - Wf);
  const size_t A1 = 32 * 112 * 112;   // 401408 per image
  const size_t A2 = 64 * 112 * 112;   // 802816 per image
  const size_t A3 = 128 * 56 * 56;    // 401408 per image
  const size_t perimg = A1 + A2 + A3; // 1605632 floats/img

  // chunk selection depends only on ws_size (constant) -> graph-capture safe
  int chunk = 1;
  for (int c = 64; c >= 1; c >>= 1)
    if ((fixedf + (size_t)c * perimg) * sizeof(float) <= ws_size) {
      chunk = c;
      break;
    }
  float* act1 = actbase;
  float* act2 = act1 + (size_t)chunk * A1;
  float* act3 = act2 + (size_t)chunk * A2;

  // ---- weight prep ----
  ternarize_kernel<<<1, 256, 0, stream>>>(w1, q1, 864);
  ternarize_kernel<<<1, 256, 0, stream>>>(w2, q2, 18432);
  ternarize_kernel<<<1, 256, 0, stream>>>(w3, q3, 73728);
  ternarize_kernel<<<1, 256, 0, stream>>>(wl, ql, 1280);
  bnfold_kernel<<<1, 64, 0, stream>>>(g1, b1, m1, v1, s1, bb1, 32);
  bnfold_kernel<<<1, 64, 0, stream>>>(g2, b2, m2, v2, s2, bb2, 64);
  bnfold_kernel<<<1, 128, 0, stream>>>(g3, b3, m3, v3, s3, bb3, 128);

  // ---- conv pipeline, chunked over batch ----
  for (int n0 = 0; n0 < 64; n0 += chunk) {
    conv3x3_bn_relu<3, 8, 2><<<dim3(49, 4, chunk), 256, 0, stream>>>(
        x + (size_t)n0 * 3 * 224 * 224, q1, s1, bb1, act1, 224, 224, 112, 112,
        32);
    conv3x3_bn_relu<32, 8, 1><<<dim3(49, 8, chunk), 256, 0, stream>>>(
        act1, q2, s2, bb2, act2, 112, 112, 112, 112, 64);
    conv3x3_bn_relu<64, 8, 2><<<dim3(13, 16, chunk), 256, 0, stream>>>(
        act2, q3, s3, bb3, act3, 112, 112, 56, 56, 128);
    pool_kernel<<<dim3(128, chunk), 256, 0, stream>>>(act3, pooled, n0, 128,
                                                      3136);
  }

  // ---- classifier head ----
  linear_kernel<<<3, 256, 0, stream>>>(pooled, ql, bl, out);
}

// Round 2
// 689.296 us; speedup vs baseline: 3.3915x; 3.3915x over previous
//
#include <hip/hip_runtime.h>
#include <cstddef>

typedef __attribute__((ext_vector_type(8))) short short8;
typedef __attribute__((ext_vector_type(4))) float floatx4;

// ---------------------------------------------------------------- bf16 utils
__device__ __forceinline__ unsigned short f2bf(float f) {
  union { float f; unsigned u; } v; v.f = f;
  const unsigned r = v.u + 0x7fffu + ((v.u >> 16) & 1u);  // RNE
  return (unsigned short)(r >> 16);
}
__device__ __forceinline__ float bf2f(unsigned short u) {
  union { unsigned u; float f; } v; v.u = ((unsigned)u) << 16;
  return v.f;
}

// ---------------------------------------------------------------- reductions
__device__ __forceinline__ float block_reduce_sum(float v, float* sm) {
#pragma unroll
  for (int off = 32; off > 0; off >>= 1) v += __shfl_down(v, off, 64);
  const int lane = threadIdx.x & 63, wid = threadIdx.x >> 6;
  __syncthreads();
  if (lane == 0) sm[wid] = v;
  __syncthreads();
  if (threadIdx.x == 0) {
    float t = 0.f;
    const int nw = (blockDim.x + 63) >> 6;
    for (int i = 0; i < nw; ++i) t += sm[i];
    sm[0] = t;
  }
  __syncthreads();
  return sm[0];
}

// ---------------------------------------------------------------- ternarize
__global__ void ternarize_kernel(const float* __restrict__ w,
                                 float* __restrict__ q, int n,
                                 float* __restrict__ alpha_out) {
  __shared__ float sm[8];
  float s = 0.f;
  for (int i = threadIdx.x; i < n; i += blockDim.x) s += fabsf(w[i]);
  const float total = block_reduce_sum(s, sm);
  const float delta = 0.7f * total / (float)n;
  float s1 = 0.f, s2 = 0.f;
  for (int i = threadIdx.x; i < n; i += blockDim.x) {
    const float a = fabsf(w[i]);
    if (a > delta) { s1 += 1.f; s2 += a; }
  }
  const float cnt  = block_reduce_sum(s1, sm);
  const float asum = block_reduce_sum(s2, sm);
  const float alpha = asum / fmaxf(cnt, 1.f);
  for (int i = threadIdx.x; i < n; i += blockDim.x) {
    const float wi = w[i];
    q[i] = (fabsf(wi) > delta) ? copysignf(alpha, wi) : 0.f;
  }
  if (alpha_out != nullptr && threadIdx.x == 0) alpha_out[0] = alpha;
}

// ---------------------------------------------------------------- BN fold
// scale = (alpha?) * g/sqrt(v+eps); bias = b - m*g/sqrt(v+eps)
__global__ void bnfold_kernel(const float* __restrict__ g,
                              const float* __restrict__ b,
                              const float* __restrict__ m,
                              const float* __restrict__ v,
                              float* __restrict__ scale,
                              float* __restrict__ bias, int n,
                              const float* __restrict__ alpha) {
  const int i = blockIdx.x * blockDim.x + threadIdx.x;
  if (i < n) {
    const float inv = g[i] / sqrtf(v[i] + 1e-5f);
    const float a = (alpha != nullptr) ? alpha[0] : 1.f;
    scale[i] = a * inv;
    bias[i]  = b[i] - m[i] * inv;
  }
}

// ---------------------------------------------------------------- weight pack
// q (OIHW fp32, values ±alpha/0) -> bp as SIGNS (+1/-1/0 bf16, exact),
// GEMM layout k = (kh*3+kw)*CIN + ic, stored k-inner-8: ((k>>3)*COUT+n)*8+(k&7)
template <int CIN, int COUT>
__global__ void pack_weights(const float* __restrict__ q,
                             unsigned short* __restrict__ bp) {
  constexpr int K = CIN * 9;
  const int idx = blockIdx.x * 256 + threadIdx.x;
  if (idx >= K * COUT) return;
  const int k = idx / COUT, n = idx % COUT;
  const int tap = k / CIN, ic = k % CIN;
  const int kh = tap / 3, kw = tap % 3;
  const float w = q[(((size_t)n * CIN + ic) * 3 + kh) * 3 + kw];
  const unsigned short sgn = (w > 0.f) ? 0x3F80u : (w < 0.f ? 0xBF80u : 0u);
  bp[((size_t)(k >> 3) * COUT + n) * 8 + (k & 7)] = sgn;
}

// ---------------------------------------------------------------- conv1
// Direct fp32 conv, stride 2, pad 1, CIN=3. Thread = 2 adjacent ow pixels x
// 8 oc. Output NHWC bf16 [64][112][112][32].
__global__ __launch_bounds__(256) void conv1_bn_relu(
    const float* __restrict__ x, const float* __restrict__ q,
    const float* __restrict__ scale, const float* __restrict__ bias,
    unsigned short* __restrict__ y) {
  __shared__ float wsm[8 * 27];
  const int oc0 = blockIdx.y * 8;
  for (int i = threadIdx.x; i < 8 * 27; i += 256) wsm[i] = q[oc0 * 27 + i];
  __syncthreads();
  const int s2 = blockIdx.x * 256 + threadIdx.x;  // pixel-pair id
  if (s2 >= 112 * 56) return;
  const int oh = s2 / 56, ow0 = (s2 % 56) * 2;
  float acc0[8], acc1[8];
#pragma unroll
  for (int j = 0; j < 8; ++j) { acc0[j] = 0.f; acc1[j] = 0.f; }
  const int ih0 = oh * 2 - 1, iw0 = ow0 * 2 - 1;
  const float* xn = x + (size_t)blockIdx.z * 3 * 224 * 224;
  for (int ic = 0; ic < 3; ++ic) {
    const float* xc = xn + (size_t)ic * 224 * 224;
#pragma unroll
    for (int kh = 0; kh < 3; ++kh) {
      const int ih = ih0 + kh;
      if ((unsigned)ih >= 224u) continue;
      const float* xr = xc + (size_t)ih * 224;
      float c[5];
#pragma unroll
      for (int j = 0; j < 5; ++j) {
        const int iw = iw0 + j;
        c[j] = ((unsigned)iw < 224u) ? xr[iw] : 0.f;
      }
#pragma unroll
      for (int kw = 0; kw < 3; ++kw) {
        const int wi = ic * 9 + kh * 3 + kw;
#pragma unroll
        for (int j = 0; j < 8; ++j) {
          const float wv = wsm[j * 27 + wi];
          acc0[j] += c[kw] * wv;
          acc1[j] += c[kw + 2] * wv;
        }
      }
    }
  }
  const size_t p0 = (size_t)blockIdx.z * 12544 + (size_t)oh * 112 + ow0;
  unsigned pk0[4], pk1[4];
#pragma unroll
  for (int h = 0; h < 4; ++h) {
    const float s0 = scale[oc0 + 2 * h], s1 = scale[oc0 + 2 * h + 1];
    const float b0 = bias[oc0 + 2 * h], b1 = bias[oc0 + 2 * h + 1];
    const float a0 = fmaxf(acc0[2 * h] * s0 + b0, 0.f);
    const float a1 = fmaxf(acc0[2 * h + 1] * s1 + b1, 0.f);
    const float c0 = fmaxf(acc1[2 * h] * s0 + b0, 0.f);
    const float c1 = fmaxf(acc1[2 * h + 1] * s1 + b1, 0.f);
    pk0[h] = (unsigned)f2bf(a0) | ((unsigned)f2bf(a1) << 16);
    pk1[h] = (unsigned)f2bf(c0) | ((unsigned)f2bf(c1) << 16);
  }
  *(uint4*)(y + p0 * 32 + oc0) = make_uint4(pk0[0], pk0[1], pk0[2], pk0[3]);
  *(uint4*)(y + (p0 + 1) * 32 + oc0) = make_uint4(pk1[0], pk1[1], pk1[2], pk1[3]);
}

// ---------------------------------------------------------------- implicit GEMM
// NHWC bf16 in/out. C[M=Nimg*OH*OW][COUT] = im2col(A) * B, K = 9*CIN,
// k = (kh*3+kw)*CIN + ic. Block: BM=128 x BN=64, BK=32, 4 waves, each wave
// 32(M)x64(N) via 2x4 mfma_f32_16x16x32_bf16 frags. Weights are +/-1/0
// (alpha folded into scale). LDS rows padded to 40 elems -> 2-way bank
// aliasing only (free, m136).
template <int CIN, int COUT, int STRIDE, int H, int W, int OH, int OW>
__global__ __launch_bounds__(256) void conv_igemm(
    const unsigned short* __restrict__ xin,
    const unsigned short* __restrict__ bp,
    const float* __restrict__ scale, const float* __restrict__ bias,
    unsigned short* __restrict__ yout) {
  constexpr int BM = 128, BN = 64, BK = 32;
  constexpr int K = CIN * 9;
  constexpr int NSTEP = K / BK;
  constexpr int SPT = CIN / BK;  // K-steps per tap (1 for CIN=32, 2 for 64)
  constexpr int APAD = 40;
  __shared__ unsigned short Abuf[BM * APAD];
  __shared__ unsigned short Bbuf[BN * APAD];
  const int t = threadIdx.x;
  const int n0 = blockIdx.y * BN;
  const int wave = t >> 6, lane = t & 63, quad = lane >> 4, l16 = lane & 15;

  // per-thread A-staging rows (2 x 16B per thread per K-step)
  int imgA[2], ohA[2], owA[2], rA[2], segA[2];
#pragma unroll
  for (int it = 0; it < 2; ++it) {
    const int li = it * 256 + t;
    rA[it] = li >> 2;
    segA[it] = li & 3;
    const int m = blockIdx.x * BM + rA[it];
    imgA[it] = m / (OH * OW);
    const int pix = m % (OH * OW);
    ohA[it] = pix / OW;
    owA[it] = pix % OW;
  }

  floatx4 acc[2][4];
#pragma unroll
  for (int mf = 0; mf < 2; ++mf)
#pragma unroll
    for (int nf = 0; nf < 4; ++nf) acc[mf][nf] = (floatx4){0.f, 0.f, 0.f, 0.f};

  for (int kt = 0; kt < NSTEP; ++kt) {
    __syncthreads();  // previous iteration's reads done before overwrite
    // ---- stage B slice (32 k x 64 n = 4KB): thread copies one 16B cell
    {
      const int kg = kt * 4 + (t >> 6), n = t & 63;
      *(uint4*)(&Bbuf[n * APAD + (t >> 6) * 8]) =
          *(const uint4*)(bp + ((size_t)kg * COUT + n0 + n) * 8);
    }
    // ---- stage A tile (128 rows x 32 k = 8KB): im2col gather
    const int tap = kt / SPT, ic0 = (kt % SPT) * BK;
    const int kh = tap / 3, kw = tap % 3;
#pragma unroll
    for (int it = 0; it < 2; ++it) {
      const int ih = ohA[it] * STRIDE + kh - 1;
      const int iw = owA[it] * STRIDE + kw - 1;
      uint4 v = make_uint4(0u, 0u, 0u, 0u);
      if ((unsigned)ih < (unsigned)H && (unsigned)iw < (unsigned)W)
        v = *(const uint4*)(xin + (((size_t)imgA[it] * H + ih) * W + iw) * CIN +
                            ic0 + segA[it] * 8);
      *(uint4*)(&Abuf[rA[it] * APAD + segA[it] * 8]) = v;
    }
    __syncthreads();
    // ---- compute
    short8 bfr[4];
#pragma unroll
    for (int nf = 0; nf < 4; ++nf)
      bfr[nf] = *(const short8*)(&Bbuf[(nf * 16 + l16) * APAD + quad * 8]);
#pragma unroll
    for (int mf = 0; mf < 2; ++mf) {
      const short8 a = *(const short8*)(
          &Abuf[(wave * 32 + mf * 16 + l16) * APAD + quad * 8]);
#pragma unroll
      for (int nf = 0; nf < 4; ++nf)
        acc[mf][nf] = __builtin_amdgcn_mfma_f32_16x16x32_bf16(
            a, bfr[nf], acc[mf][nf], 0, 0, 0);
    }
  }

  // ---- epilogue: BN + ReLU, bf16 NHWC store
  float sc[4], bs[4];
#pragma unroll
  for (int nf = 0; nf < 4; ++nf) {
    sc[nf] = scale[n0 + nf * 16 + l16];
    bs[nf] = bias[n0 + nf * 16 + l16];
  }
#pragma unroll
  for (int mf = 0; mf < 2; ++mf)
#pragma unroll
    for (int nf = 0; nf < 4; ++nf)
#pragma unroll
      for (int r = 0; r < 4; ++r) {
        const int row = wave * 32 + mf * 16 + quad * 4 + r;
        const size_t m = (size_t)blockIdx.x * BM + row;
        const float vv = fmaxf(acc[mf][nf][r] * sc[nf] + bs[nf], 0.f);
        yout[m * COUT + n0 + nf * 16 + l16] = f2bf(vv);
      }
}

// ---------------------------------------------------------------- pool (NHWC)
__global__ __launch_bounds__(256) void pool_part(
    const unsigned short* __restrict__ a, float* __restrict__ part) {
  __shared__ float sm[256];
  const int n = blockIdx.x, j = blockIdx.y, t = threadIdx.x;
  const int c = t & 127, h = t >> 7;
  const unsigned short* p = a + (size_t)n * 3136 * 128;
  float s = 0.f;
  for (int px = j * 784 + h; px < (j + 1) * 784; px += 2)
    s += bf2f(p[(size_t)px * 128 + c]);
  sm[t] = s;
  __syncthreads();
  if (t < 128) part[((size_t)n * 4 + j) * 128 + t] = sm[t] + sm[t + 128];
}

__global__ void pool_final(const float* __restrict__ part,
                           float* __restrict__ pooled) {
  const int idx = blockIdx.x * 256 + threadIdx.x;
  if (idx >= 64 * 128) return;
  const int n = idx >> 7, c = idx & 127;
  float s = 0.f;
#pragma unroll
  for (int j = 0; j < 4; ++j) s += part[((size_t)n * 4 + j) * 128 + c];
  pooled[idx] = s * (1.f / 3136.f);
}

// ---------------------------------------------------------------- linear
__global__ void linear_kernel(const float* __restrict__ pooled,
                              const float* __restrict__ ql,
                              const float* __restrict__ bl,
                              float* __restrict__ out) {
  const int idx = blockIdx.x * blockDim.x + threadIdx.x;
  if (idx >= 64 * 10) return;
  const int n = idx / 10, o = idx % 10;
  const float* p = pooled + (size_t)n * 128;
  const float* w = ql + (size_t)o * 128;
  float s = 0.f;
#pragma unroll 4
  for (int c = 0; c < 128; ++c) s += p[c] * w[c];
  out[idx] = s + bl[o];
}

// ---------------------------------------------------------------- launch
extern "C" void kernel_launch(void* const* d_in, const int* in_sizes, int n_in,
                              void* d_out, int out_size, void* d_ws,
                              size_t ws_size, hipStream_t stream) {
  const float* x  = (const float*)d_in[0];
  const float* w1 = (const float*)d_in[1];
  const float* g1 = (const float*)d_in[2];
  const float* b1 = (const float*)d_in[3];
  const float* m1 = (const float*)d_in[4];
  const float* v1 = (const float*)d_in[5];
  const float* w2 = (const float*)d_in[6];
  const float* g2 = (const float*)d_in[7];
  const float* b2 = (const float*)d_in[8];
  const float* m2 = (const float*)d_in[9];
  const float* v2 = (const float*)d_in[10];
  const float* w3 = (const float*)d_in[11];
  const float* g3 = (const float*)d_in[12];
  const float* b3 = (const float*)d_in[13];
  const float* m3 = (const float*)d_in[14];
  const float* v3 = (const float*)d_in[15];
  const float* wl = (const float*)d_in[16];
  const float* bl = (const float*)d_in[17];
  float* out = (float*)d_out;

  // ---- workspace layout ----
  float* Wf = (float*)d_ws;
  float* q1 = Wf;                 // 864
  float* q2 = q1 + 864;           // 18432
  float* q3 = q2 + 18432;         // 73728
  float* ql = q3 + 73728;         // 1280
  float* s1 = ql + 1280;  float* bb1 = s1 + 32;
  float* s2 = bb1 + 32;   float* bb2 = s2 + 64;
  float* s3 = bb2 + 64;   float* bb3 = s3 + 128;
  float* al2 = bb3 + 128; float* al3 = al2 + 4;
  float* pooled = al3 + 4;        // 8192
  float* part = pooled + 8192;    // 64*4*128 = 32768
  unsigned short* Us = (unsigned short*)(part + 32768);
  unsigned short* bp2 = Us;                 // 288*64   = 18432
  unsigned short* bp3 = bp2 + 18432;        // 576*128  = 73728
  unsigned short* act1 = bp3 + 73728;       // 64*12544*32 = 25690112
  unsigned short* act2 = act1 + 25690112;   // 64*12544*64 = 51380224
  unsigned short* act3 = act1;              // act1 dead after conv2: alias
  // total ~155 MB < ws_size (>=205 MB proven by R1 chunk=32 selection)

  // ---- weight prep ----
  ternarize_kernel<<<1, 256, 0, stream>>>(w1, q1, 864, nullptr);
  ternarize_kernel<<<1, 256, 0, stream>>>(w2, q2, 18432, al2);
  ternarize_kernel<<<1, 256, 0, stream>>>(w3, q3, 73728, al3);
  ternarize_kernel<<<1, 256, 0, stream>>>(wl, ql, 1280, nullptr);
  bnfold_kernel<<<1, 64, 0, stream>>>(g1, b1, m1, v1, s1, bb1, 32, nullptr);
  bnfold_kernel<<<1, 64, 0, stream>>>(g2, b2, m2, v2, s2, bb2, 64, al2);
  bnfold_kernel<<<1, 128, 0, stream>>>(g3, b3, m3, v3, s3, bb3, 128, al3);
  pack_weights<32, 64><<<72, 256, 0, stream>>>(q2, bp2);
  pack_weights<64, 128><<<288, 256, 0, stream>>>(q3, bp3);

  // ---- network ----
  conv1_bn_relu<<<dim3(25, 4, 64), 256, 0, stream>>>(x, q1, s1, bb1, act1);
  conv_igemm<32, 64, 1, 112, 112, 112, 112>
      <<<dim3(6272, 1), 256, 0, stream>>>(act1, bp2, s2, bb2, act2);
  conv_igemm<64, 128, 2, 112, 112, 56, 56>
      <<<dim3(1568, 2), 256, 0, stream>>>(act2, bp3, s3, bb3, act3);
  pool_part<<<dim3(64, 4), 256, 0, stream>>>(act3, part);
  pool_final<<<32, 256, 0, stream>>>(part, pooled);
  linear_kernel<<<3, 256, 0, stream>>>(pooled, ql, bl, out);
}

// Round 3
// 494.429 us; speedup vs baseline: 4.7282x; 1.3941x over previous
//
#include <hip/hip_runtime.h>
#include <cstddef>

typedef __attribute__((ext_vector_type(8))) short short8;
typedef __attribute__((ext_vector_type(4))) float floatx4;

// ---------------------------------------------------------------- bf16 utils
__device__ __forceinline__ unsigned short f2bf(float f) {
  union { float f; unsigned u; } v; v.f = f;
  const unsigned r = v.u + 0x7fffu + ((v.u >> 16) & 1u);  // RNE
  return (unsigned short)(r >> 16);
}
__device__ __forceinline__ float bf2f(unsigned short u) {
  union { unsigned u; float f; } v; v.u = ((unsigned)u) << 16;
  return v.f;
}

// ---------------------------------------------------------------- reductions
__device__ __forceinline__ float block_reduce_sum(float v, float* sm) {
#pragma unroll
  for (int off = 32; off > 0; off >>= 1) v += __shfl_down(v, off, 64);
  const int lane = threadIdx.x & 63, wid = threadIdx.x >> 6;
  __syncthreads();
  if (lane == 0) sm[wid] = v;
  __syncthreads();
  if (threadIdx.x == 0) {
    float t = 0.f;
    const int nw = (blockDim.x + 63) >> 6;
    for (int i = 0; i < nw; ++i) t += sm[i];
    sm[0] = t;
  }
  __syncthreads();
  return sm[0];
}

// ---------------------------------------------------------------- ternarize
// Grid-parallel 3-phase TWN over all 4 weight tensors at once.
// red[t*4+0]=sum|w|, red[t*4+1]=masked count, red[t*4+2]=masked sum|w|.
// Tensor order t: 0=w1, 1=w2, 2=w3, 3=wl.
__device__ __forceinline__ void tsel(int t, const float* w0, const float* w1,
                                     const float* w2, const float* w3, int n0,
                                     int n1, int n2, int n3,
                                     const float*& w, int& n) {
  w = (t == 0) ? w0 : (t == 1) ? w1 : (t == 2) ? w2 : w3;
  n = (t == 0) ? n0 : (t == 1) ? n1 : (t == 2) ? n2 : n3;
}

__global__ __launch_bounds__(256) void tern_phase1(
    const float* w0, const float* w1, const float* w2, const float* w3,
    int n0, int n1, int n2, int n3, float* __restrict__ red) {
  __shared__ float sm[8];
  const float* w; int n;
  tsel(blockIdx.y, w0, w1, w2, w3, n0, n1, n2, n3, w, n);
  if ((int)blockIdx.x * 256 >= n) return;
  const int i = blockIdx.x * 256 + threadIdx.x;
  float s = (i < n) ? fabsf(w[i]) : 0.f;
  s = block_reduce_sum(s, sm);
  if (threadIdx.x == 0) atomicAdd(&red[blockIdx.y * 4 + 0], s);
}

__global__ __launch_bounds__(256) void tern_phase2(
    const float* w0, const float* w1, const float* w2, const float* w3,
    int n0, int n1, int n2, int n3, float* __restrict__ red) {
  __shared__ float sm[8];
  const float* w; int n;
  tsel(blockIdx.y, w0, w1, w2, w3, n0, n1, n2, n3, w, n);
  if ((int)blockIdx.x * 256 >= n) return;
  const float delta = 0.7f * red[blockIdx.y * 4 + 0] / (float)n;
  const int i = blockIdx.x * 256 + threadIdx.x;
  float c = 0.f, a = 0.f;
  if (i < n) {
    const float v = fabsf(w[i]);
    if (v > delta) { c = 1.f; a = v; }
  }
  c = block_reduce_sum(c, sm);
  a = block_reduce_sum(a, sm);
  if (threadIdx.x == 0) {
    atomicAdd(&red[blockIdx.y * 4 + 1], c);
    atomicAdd(&red[blockIdx.y * 4 + 2], a);
  }
}

// Materialize q (fp32 +/-alpha / 0) only for w1 (t=0) and wl (t=3).
__global__ __launch_bounds__(256) void tern_phase3(
    const float* __restrict__ wa, const float* __restrict__ wb, int na, int nb,
    float* __restrict__ qa, float* __restrict__ qb,
    const float* __restrict__ red) {
  const int t = blockIdx.y;                    // 0 -> w1, 1 -> wl
  const float* w = t ? wb : wa;
  float* q = t ? qb : qa;
  const int n = t ? nb : na;
  const int rb = t ? 12 : 0;
  const float delta = 0.7f * red[rb + 0] / (float)n;
  const float alpha = red[rb + 2] / fmaxf(red[rb + 1], 1.f);
  const int i = blockIdx.x * 256 + threadIdx.x;
  if (i < n) {
    const float wi = w[i];
    q[i] = (fabsf(wi) > delta) ? copysignf(alpha, wi) : 0.f;
  }
}

// ---------------------------------------------------------------- BN fold
// scale = alpha * g/sqrt(v+eps); bias = b - m*g/sqrt(v+eps); alpha from red_t
__global__ void bnfold_kernel(const float* __restrict__ g,
                              const float* __restrict__ b,
                              const float* __restrict__ m,
                              const float* __restrict__ v,
                              float* __restrict__ scale,
                              float* __restrict__ bias, int n,
                              const float* __restrict__ red_t) {
  const int i = blockIdx.x * blockDim.x + threadIdx.x;
  if (i < n) {
    const float inv = g[i] / sqrtf(v[i] + 1e-5f);
    const float a = (red_t != nullptr) ? red_t[2] / fmaxf(red_t[1], 1.f) : 1.f;
    scale[i] = a * inv;
    bias[i]  = b[i] - m[i] * inv;
  }
}

// ---------------------------------------------------------------- weight pack
// Original OIHW fp32 w -> sign bf16 (+1/-1/0, exact; alpha folded into BN
// scale). GEMM layout k = (kh*3+kw)*CIN + ic, stored ((k>>3)*COUT+n)*8+(k&7).
template <int CIN, int COUT>
__global__ void pack_weights(const float* __restrict__ w,
                             const float* __restrict__ red_t,
                             unsigned short* __restrict__ bp) {
  constexpr int K = CIN * 9;
  const float delta = 0.7f * red_t[0] / (float)(K * COUT);
  const int idx = blockIdx.x * 256 + threadIdx.x;
  if (idx >= K * COUT) return;
  const int k = idx / COUT, n = idx % COUT;
  const int tap = k / CIN, ic = k % CIN;
  const int kh = tap / 3, kw = tap % 3;
  const float v = w[(((size_t)n * CIN + ic) * 3 + kh) * 3 + kw];
  const unsigned short sgn = (v > delta) ? 0x3F80u : (v < -delta ? 0xBF80u : 0u);
  bp[((size_t)(k >> 3) * COUT + n) * 8 + (k & 7)] = sgn;
}

// ---------------------------------------------------------------- conv1
// Direct fp32 conv, stride 2, pad 1, CIN=3. Thread = 2 adjacent ow pixels x
// 8 oc. Output NHWC bf16 [64][112][112][32].
__global__ __launch_bounds__(256) void conv1_bn_relu(
    const float* __restrict__ x, const float* __restrict__ q,
    const float* __restrict__ scale, const float* __restrict__ bias,
    unsigned short* __restrict__ y) {
  __shared__ float wsm[8 * 27];
  const int oc0 = blockIdx.y * 8;
  for (int i = threadIdx.x; i < 8 * 27; i += 256) wsm[i] = q[oc0 * 27 + i];
  __syncthreads();
  const int s2 = blockIdx.x * 256 + threadIdx.x;  // pixel-pair id
  if (s2 >= 112 * 56) return;
  const int oh = s2 / 56, ow0 = (s2 % 56) * 2;
  float acc0[8], acc1[8];
#pragma unroll
  for (int j = 0; j < 8; ++j) { acc0[j] = 0.f; acc1[j] = 0.f; }
  const int ih0 = oh * 2 - 1, iw0 = ow0 * 2 - 1;
  const float* xn = x + (size_t)blockIdx.z * 3 * 224 * 224;
  for (int ic = 0; ic < 3; ++ic) {
    const float* xc = xn + (size_t)ic * 224 * 224;
#pragma unroll
    for (int kh = 0; kh < 3; ++kh) {
      const int ih = ih0 + kh;
      if ((unsigned)ih >= 224u) continue;
      const float* xr = xc + (size_t)ih * 224;
      float c[5];
#pragma unroll
      for (int j = 0; j < 5; ++j) {
        const int iw = iw0 + j;
        c[j] = ((unsigned)iw < 224u) ? xr[iw] : 0.f;
      }
#pragma unroll
      for (int kw = 0; kw < 3; ++kw) {
        const int wi = ic * 9 + kh * 3 + kw;
#pragma unroll
        for (int j = 0; j < 8; ++j) {
          const float wv = wsm[j * 27 + wi];
          acc0[j] += c[kw] * wv;
          acc1[j] += c[kw + 2] * wv;
        }
      }
    }
  }
  const size_t p0 = (size_t)blockIdx.z * 12544 + (size_t)oh * 112 + ow0;
  unsigned pk0[4], pk1[4];
#pragma unroll
  for (int h = 0; h < 4; ++h) {
    const float s0 = scale[oc0 + 2 * h], s1 = scale[oc0 + 2 * h + 1];
    const float b0 = bias[oc0 + 2 * h], b1 = bias[oc0 + 2 * h + 1];
    const float a0 = fmaxf(acc0[2 * h] * s0 + b0, 0.f);
    const float a1 = fmaxf(acc0[2 * h + 1] * s1 + b1, 0.f);
    const float c0 = fmaxf(acc1[2 * h] * s0 + b0, 0.f);
    const float c1 = fmaxf(acc1[2 * h + 1] * s1 + b1, 0.f);
    pk0[h] = (unsigned)f2bf(a0) | ((unsigned)f2bf(a1) << 16);
    pk1[h] = (unsigned)f2bf(c0) | ((unsigned)f2bf(c1) << 16);
  }
  *(uint4*)(y + p0 * 32 + oc0) = make_uint4(pk0[0], pk0[1], pk0[2], pk0[3]);
  *(uint4*)(y + (p0 + 1) * 32 + oc0) = make_uint4(pk1[0], pk1[1], pk1[2], pk1[3]);
}

// ---------------------------------------------------------------- implicit GEMM
// NHWC bf16 in/out. C[M=Nimg*OH*OW][COUT] = im2col(A) * B, K = 9*CIN,
// k = (kh*3+kw)*CIN + ic. Block: BM=128 x BN=64, BK=32, 4 waves, each wave
// 32(M)x64(N) via 2x4 mfma_f32_16x16x32_bf16 frags. Weights are +/-1/0
// (alpha folded into scale). LDS rows padded to 40 elems -> 2-way bank
// aliasing only (free, m136).
template <int CIN, int COUT, int STRIDE, int H, int W, int OH, int OW>
__global__ __launch_bounds__(256) void conv_igemm(
    const unsigned short* __restrict__ xin,
    const unsigned short* __restrict__ bp,
    const float* __restrict__ scale, const float* __restrict__ bias,
    unsigned short* __restrict__ yout) {
  constexpr int BM = 128, BN = 64, BK = 32;
  constexpr int K = CIN * 9;
  constexpr int NSTEP = K / BK;
  constexpr int SPT = CIN / BK;  // K-steps per tap (1 for CIN=32, 2 for 64)
  constexpr int APAD = 40;
  __shared__ unsigned short Abuf[BM * APAD];
  __shared__ unsigned short Bbuf[BN * APAD];
  const int t = threadIdx.x;
  const int n0 = blockIdx.y * BN;
  const int wave = t >> 6, lane = t & 63, quad = lane >> 4, l16 = lane & 15;

  // per-thread A-staging rows (2 x 16B per thread per K-step)
  int imgA[2], ohA[2], owA[2], rA[2], segA[2];
#pragma unroll
  for (int it = 0; it < 2; ++it) {
    const int li = it * 256 + t;
    rA[it] = li >> 2;
    segA[it] = li & 3;
    const int m = blockIdx.x * BM + rA[it];
    imgA[it] = m / (OH * OW);
    const int pix = m % (OH * OW);
    ohA[it] = pix / OW;
    owA[it] = pix % OW;
  }

  floatx4 acc[2][4];
#pragma unroll
  for (int mf = 0; mf < 2; ++mf)
#pragma unroll
    for (int nf = 0; nf < 4; ++nf) acc[mf][nf] = (floatx4){0.f, 0.f, 0.f, 0.f};

  for (int kt = 0; kt < NSTEP; ++kt) {
    __syncthreads();  // previous iteration's reads done before overwrite
    // ---- stage B slice (32 k x 64 n = 4KB): thread copies one 16B cell
    {
      const int kg = kt * 4 + (t >> 6), n = t & 63;
      *(uint4*)(&Bbuf[n * APAD + (t >> 6) * 8]) =
          *(const uint4*)(bp + ((size_t)kg * COUT + n0 + n) * 8);
    }
    // ---- stage A tile (128 rows x 32 k = 8KB): im2col gather
    const int tap = kt / SPT, ic0 = (kt % SPT) * BK;
    const int kh = tap / 3, kw = tap % 3;
#pragma unroll
    for (int it = 0; it < 2; ++it) {
      const int ih = ohA[it] * STRIDE + kh - 1;
      const int iw = owA[it] * STRIDE + kw - 1;
      uint4 v = make_uint4(0u, 0u, 0u, 0u);
      if ((unsigned)ih < (unsigned)H && (unsigned)iw < (unsigned)W)
        v = *(const uint4*)(xin + (((size_t)imgA[it] * H + ih) * W + iw) * CIN +
                            ic0 + segA[it] * 8);
      *(uint4*)(&Abuf[rA[it] * APAD + segA[it] * 8]) = v;
    }
    __syncthreads();
    // ---- compute
    short8 bfr[4];
#pragma unroll
    for (int nf = 0; nf < 4; ++nf)
      bfr[nf] = *(const short8*)(&Bbuf[(nf * 16 + l16) * APAD + quad * 8]);
#pragma unroll
    for (int mf = 0; mf < 2; ++mf) {
      const short8 a = *(const short8*)(
          &Abuf[(wave * 32 + mf * 16 + l16) * APAD + quad * 8]);
#pragma unroll
      for (int nf = 0; nf < 4; ++nf)
        acc[mf][nf] = __builtin_amdgcn_mfma_f32_16x16x32_bf16(
            a, bfr[nf], acc[mf][nf], 0, 0, 0);
    }
  }

  // ---- epilogue: BN + ReLU, bf16 NHWC store
  float sc[4], bs[4];
#pragma unroll
  for (int nf = 0; nf < 4; ++nf) {
    sc[nf] = scale[n0 + nf * 16 + l16];
    bs[nf] = bias[n0 + nf * 16 + l16];
  }
#pragma unroll
  for (int mf = 0; mf < 2; ++mf)
#pragma unroll
    for (int nf = 0; nf < 4; ++nf)
#pragma unroll
      for (int r = 0; r < 4; ++r) {
        const int row = wave * 32 + mf * 16 + quad * 4 + r;
        const size_t m = (size_t)blockIdx.x * BM + row;
        const float vv = fmaxf(acc[mf][nf][r] * sc[nf] + bs[nf], 0.f);
        yout[m * COUT + n0 + nf * 16 + l16] = f2bf(vv);
      }
}

// ---------------------------------------------------------------- pool (NHWC)
__global__ __launch_bounds__(256) void pool_part(
    const unsigned short* __restrict__ a, float* __restrict__ part) {
  __shared__ float sm[256];
  const int n = blockIdx.x, j = blockIdx.y, t = threadIdx.x;
  const int c = t & 127, h = t >> 7;
  const unsigned short* p = a + (size_t)n * 3136 * 128;
  float s = 0.f;
  for (int px = j * 784 + h; px < (j + 1) * 784; px += 2)
    s += bf2f(p[(size_t)px * 128 + c]);
  sm[t] = s;
  __syncthreads();
  if (t < 128) part[((size_t)n * 4 + j) * 128 + t] = sm[t] + sm[t + 128];
}

__global__ void pool_final(const float* __restrict__ part,
                           float* __restrict__ pooled) {
  const int idx = blockIdx.x * 256 + threadIdx.x;
  if (idx >= 64 * 128) return;
  const int n = idx >> 7, c = idx & 127;
  float s = 0.f;
#pragma unroll
  for (int j = 0; j < 4; ++j) s += part[((size_t)n * 4 + j) * 128 + c];
  pooled[idx] = s * (1.f / 3136.f);
}

// ---------------------------------------------------------------- linear
__global__ void linear_kernel(const float* __restrict__ pooled,
                              const float* __restrict__ ql,
                              const float* __restrict__ bl,
                              float* __restrict__ out) {
  const int idx = blockIdx.x * blockDim.x + threadIdx.x;
  if (idx >= 64 * 10) return;
  const int n = idx / 10, o = idx % 10;
  const float* p = pooled + (size_t)n * 128;
  const float* w = ql + (size_t)o * 128;
  float s = 0.f;
#pragma unroll 4
  for (int c = 0; c < 128; ++c) s += p[c] * w[c];
  out[idx] = s + bl[o];
}

// ---------------------------------------------------------------- launch
extern "C" void kernel_launch(void* const* d_in, const int* in_sizes, int n_in,
                              void* d_out, int out_size, void* d_ws,
                              size_t ws_size, hipStream_t stream) {
  const float* x  = (const float*)d_in[0];
  const float* w1 = (const float*)d_in[1];
  const float* g1 = (const float*)d_in[2];
  const float* b1 = (const float*)d_in[3];
  const float* m1 = (const float*)d_in[4];
  const float* v1 = (const float*)d_in[5];
  const float* w2 = (const float*)d_in[6];
  const float* g2 = (const float*)d_in[7];
  const float* b2 = (const float*)d_in[8];
  const float* m2 = (const float*)d_in[9];
  const float* v2 = (const float*)d_in[10];
  const float* w3 = (const float*)d_in[11];
  const float* g3 = (const float*)d_in[12];
  const float* b3 = (const float*)d_in[13];
  const float* m3 = (const float*)d_in[14];
  const float* v3 = (const float*)d_in[15];
  const float* wl = (const float*)d_in[16];
  const float* bl = (const float*)d_in[17];
  float* out = (float*)d_out;

  // ---- workspace layout ----
  float* Wf = (float*)d_ws;
  float* red = Wf;                // 16 (4 tensors x {sum, cnt, asum, pad})
  float* q1 = red + 16;           // 864
  float* ql = q1 + 864;           // 1280
  float* s1 = ql + 1280;  float* bb1 = s1 + 32;
  float* s2 = bb1 + 32;   float* bb2 = s2 + 64;
  float* s3 = bb2 + 64;   float* bb3 = s3 + 128;
  float* pooled = bb3 + 128;      // 8192
  float* part = pooled + 8192;    // 64*4*128 = 32768
  unsigned short* Us = (unsigned short*)(part + 32768);
  unsigned short* bp2 = Us;                 // 288*64   = 18432
  unsigned short* bp3 = bp2 + 18432;        // 576*128  = 73728
  unsigned short* act1 = bp3 + 73728;       // 64*12544*32 = 25690112
  unsigned short* act2 = act1 + 25690112;   // 64*12544*64 = 51380224
  unsigned short* act3 = act1;              // act1 dead after conv2: alias
  // total ~155 MB < ws_size (>=205 MB proven by R1 chunk=32 selection)

  // ---- ternarize (grid-parallel, 3 phases over all 4 tensors) ----
  hipMemsetAsync(red, 0, 16 * sizeof(float), stream);
  // grid.x covers max n = 73728 -> 288 blocks
  tern_phase1<<<dim3(288, 4), 256, 0, stream>>>(w1, w2, w3, wl, 864, 18432,
                                                73728, 1280, red);
  tern_phase2<<<dim3(288, 4), 256, 0, stream>>>(w1, w2, w3, wl, 864, 18432,
                                                73728, 1280, red);
  tern_phase3<<<dim3(5, 2), 256, 0, stream>>>(w1, wl, 864, 1280, q1, ql, red);

  bnfold_kernel<<<1, 64, 0, stream>>>(g1, b1, m1, v1, s1, bb1, 32, nullptr);
  bnfold_kernel<<<1, 64, 0, stream>>>(g2, b2, m2, v2, s2, bb2, 64, red + 4);
  bnfold_kernel<<<1, 128, 0, stream>>>(g3, b3, m3, v3, s3, bb3, 128, red + 8);
  pack_weights<32, 64><<<72, 256, 0, stream>>>(w2, red + 4, bp2);
  pack_weights<64, 128><<<288, 256, 0, stream>>>(w3, red + 8, bp3);

  // ---- network ----
  conv1_bn_relu<<<dim3(25, 4, 64), 256, 0, stream>>>(x, q1, s1, bb1, act1);
  conv_igemm<32, 64, 1, 112, 112, 112, 112>
      <<<dim3(6272, 1), 256, 0, stream>>>(act1, bp2, s2, bb2, act2);
  conv_igemm<64, 128, 2, 112, 112, 56, 56>
      <<<dim3(1568, 2), 256, 0, stream>>>(act2, bp3, s3, bb3, act3);
  pool_part<<<dim3(64, 4), 256, 0, stream>>>(act3, part);
  pool_final<<<32, 256, 0, stream>>>(part, pooled);
  linear_kernel<<<3, 256, 0, stream>>>(pooled, ql, bl, out);
}

// Round 5
// 485.703 us; speedup vs baseline: 4.8132x; 1.0180x over previous
//
#include <hip/hip_runtime.h>
#include <cstddef>

typedef __attribute__((ext_vector_type(8))) short short8;
typedef __attribute__((ext_vector_type(4))) float floatx4;

// ---------------------------------------------------------------- bf16 utils
__device__ __forceinline__ unsigned short f2bf(float f) {
  union { float f; unsigned u; } v; v.f = f;
  const unsigned r = v.u + 0x7fffu + ((v.u >> 16) & 1u);  // RNE
  return (unsigned short)(r >> 16);
}
__device__ __forceinline__ float bf2f(unsigned short u) {
  union { unsigned u; float f; } v; v.u = ((unsigned)u) << 16;
  return v.f;
}

// ---------------------------------------------------------------- reductions
__device__ __forceinline__ float block_reduce_sum(float v, float* sm) {
#pragma unroll
  for (int off = 32; off > 0; off >>= 1) v += __shfl_down(v, off, 64);
  const int lane = threadIdx.x & 63, wid = threadIdx.x >> 6;
  __syncthreads();
  if (lane == 0) sm[wid] = v;
  __syncthreads();
  if (threadIdx.x == 0) {
    float t = 0.f;
    const int nw = (blockDim.x + 63) >> 6;
    for (int i = 0; i < nw; ++i) t += sm[i];
    sm[0] = t;
  }
  __syncthreads();
  return sm[0];
}

// ---------------------------------------------------------------- ternarize
// Grid-parallel 3-phase TWN over all 4 weight tensors at once.
// red[t*4+0]=sum|w|, red[t*4+1]=masked count, red[t*4+2]=masked sum|w|.
__device__ __forceinline__ void tsel(int t, const float* w0, const float* w1,
                                     const float* w2, const float* w3, int n0,
                                     int n1, int n2, int n3,
                                     const float*& w, int& n) {
  w = (t == 0) ? w0 : (t == 1) ? w1 : (t == 2) ? w2 : w3;
  n = (t == 0) ? n0 : (t == 1) ? n1 : (t == 2) ? n2 : n3;
}

__global__ __launch_bounds__(256) void tern_phase1(
    const float* w0, const float* w1, const float* w2, const float* w3,
    int n0, int n1, int n2, int n3, float* __restrict__ red) {
  __shared__ float sm[8];
  const float* w; int n;
  tsel(blockIdx.y, w0, w1, w2, w3, n0, n1, n2, n3, w, n);
  if ((int)blockIdx.x * 256 >= n) return;
  const int i = blockIdx.x * 256 + threadIdx.x;
  float s = (i < n) ? fabsf(w[i]) : 0.f;
  s = block_reduce_sum(s, sm);
  if (threadIdx.x == 0) atomicAdd(&red[blockIdx.y * 4 + 0], s);
}

__global__ __launch_bounds__(256) void tern_phase2(
    const float* w0, const float* w1, const float* w2, const float* w3,
    int n0, int n1, int n2, int n3, float* __restrict__ red) {
  __shared__ float sm[8];
  const float* w; int n;
  tsel(blockIdx.y, w0, w1, w2, w3, n0, n1, n2, n3, w, n);
  if ((int)blockIdx.x * 256 >= n) return;
  const float delta = 0.7f * red[blockIdx.y * 4 + 0] / (float)n;
  const int i = blockIdx.x * 256 + threadIdx.x;
  float c = 0.f, a = 0.f;
  if (i < n) {
    const float v = fabsf(w[i]);
    if (v > delta) { c = 1.f; a = v; }
  }
  c = block_reduce_sum(c, sm);
  a = block_reduce_sum(a, sm);
  if (threadIdx.x == 0) {
    atomicAdd(&red[blockIdx.y * 4 + 1], c);
    atomicAdd(&red[blockIdx.y * 4 + 2], a);
  }
}

// Materialize q (fp32 +/-alpha / 0) only for w1 (t=0) and wl (t=1 -> wl).
__global__ __launch_bounds__(256) void tern_phase3(
    const float* __restrict__ wa, const float* __restrict__ wb, int na, int nb,
    float* __restrict__ qa, float* __restrict__ qb,
    const float* __restrict__ red) {
  const int t = blockIdx.y;                    // 0 -> w1, 1 -> wl
  const float* w = t ? wb : wa;
  float* q = t ? qb : qa;
  const int n = t ? nb : na;
  const int rb = t ? 12 : 0;
  const float delta = 0.7f * red[rb + 0] / (float)n;
  const float alpha = red[rb + 2] / fmaxf(red[rb + 1], 1.f);
  const int i = blockIdx.x * 256 + threadIdx.x;
  if (i < n) {
    const float wi = w[i];
    q[i] = (fabsf(wi) > delta) ? copysignf(alpha, wi) : 0.f;
  }
}

// ---------------------------------------------------------------- BN fold
// One launch for all three BN layers. scale = alpha*g/sqrt(v+eps),
// bias = b - m*g/sqrt(v+eps). L1 has no alpha (conv1 uses materialized q1).
__global__ void bnfold_all(
    const float* g1, const float* b1, const float* m1, const float* v1,
    const float* g2, const float* b2, const float* m2, const float* v2,
    const float* g3, const float* b3, const float* m3, const float* v3,
    float* s1, float* bb1, float* s2, float* bb2, float* s3, float* bb3,
    const float* __restrict__ red) {
  const int i = threadIdx.x;
  if (i < 32) {
    const float inv = g1[i] / sqrtf(v1[i] + 1e-5f);
    s1[i] = inv; bb1[i] = b1[i] - m1[i] * inv;
  } else if (i < 96) {
    const int c = i - 32;
    const float inv = g2[c] / sqrtf(v2[c] + 1e-5f);
    const float a = red[6] / fmaxf(red[5], 1.f);
    s2[c] = a * inv; bb2[c] = b2[c] - m2[c] * inv;
  } else if (i < 224) {
    const int c = i - 96;
    const float inv = g3[c] / sqrtf(v3[c] + 1e-5f);
    const float a = red[10] / fmaxf(red[9], 1.f);
    s3[c] = a * inv; bb3[c] = b3[c] - m3[c] * inv;
  }
}

// ---------------------------------------------------------------- weight pack
// Original OIHW fp32 w -> sign bf16 (+1/-1/0, exact; alpha folded into BN
// scale). GEMM layout k = (kh*3+kw)*CIN + ic, stored ((k>>3)*COUT+n)*8+(k&7).
template <int CIN, int COUT>
__global__ void pack_weights(const float* __restrict__ w,
                             const float* __restrict__ red_t,
                             unsigned short* __restrict__ bp) {
  constexpr int K = CIN * 9;
  const float delta = 0.7f * red_t[0] / (float)(K * COUT);
  const int idx = blockIdx.x * 256 + threadIdx.x;
  if (idx >= K * COUT) return;
  const int k = idx / COUT, n = idx % COUT;
  const int tap = k / CIN, ic = k % CIN;
  const int kh = tap / 3, kw = tap % 3;
  const float v = w[(((size_t)n * CIN + ic) * 3 + kh) * 3 + kw];
  const unsigned short sgn = (v > delta) ? 0x3F80u : (v < -delta ? 0xBF80u : 0u);
  bp[((size_t)(k >> 3) * COUT + n) * 8 + (k & 7)] = sgn;
}

// ---------------------------------------------------------------- conv1
// Direct fp32 conv, stride 2, pad 1, CIN=3. Thread = 2 adjacent ow pixels x
// 8 oc. Output NHWC bf16 [64][112][112][32].
__global__ __launch_bounds__(256) void conv1_bn_relu(
    const float* __restrict__ x, const float* __restrict__ q,
    const float* __restrict__ scale, const float* __restrict__ bias,
    unsigned short* __restrict__ y) {
  __shared__ float wsm[8 * 27];
  const int oc0 = blockIdx.y * 8;
  for (int i = threadIdx.x; i < 8 * 27; i += 256) wsm[i] = q[oc0 * 27 + i];
  __syncthreads();
  const int s2 = blockIdx.x * 256 + threadIdx.x;  // pixel-pair id
  if (s2 >= 112 * 56) return;
  const int oh = s2 / 56, ow0 = (s2 % 56) * 2;
  float acc0[8], acc1[8];
#pragma unroll
  for (int j = 0; j < 8; ++j) { acc0[j] = 0.f; acc1[j] = 0.f; }
  const int ih0 = oh * 2 - 1, iw0 = ow0 * 2 - 1;
  const float* xn = x + (size_t)blockIdx.z * 3 * 224 * 224;
  for (int ic = 0; ic < 3; ++ic) {
    const float* xc = xn + (size_t)ic * 224 * 224;
#pragma unroll
    for (int kh = 0; kh < 3; ++kh) {
      const int ih = ih0 + kh;
      if ((unsigned)ih >= 224u) continue;
      const float* xr = xc + (size_t)ih * 224;
      float c[5];
#pragma unroll
      for (int j = 0; j < 5; ++j) {
        const int iw = iw0 + j;
        c[j] = ((unsigned)iw < 224u) ? xr[iw] : 0.f;
      }
#pragma unroll
      for (int kw = 0; kw < 3; ++kw) {
        const int wi = ic * 9 + kh * 3 + kw;
#pragma unroll
        for (int j = 0; j < 8; ++j) {
          const float wv = wsm[j * 27 + wi];
          acc0[j] += c[kw] * wv;
          acc1[j] += c[kw + 2] * wv;
        }
      }
    }
  }
  const size_t p0 = (size_t)blockIdx.z * 12544 + (size_t)oh * 112 + ow0;
  unsigned pk0[4], pk1[4];
#pragma unroll
  for (int h = 0; h < 4; ++h) {
    const float s0 = scale[oc0 + 2 * h], s1 = scale[oc0 + 2 * h + 1];
    const float b0 = bias[oc0 + 2 * h], b1 = bias[oc0 + 2 * h + 1];
    const float a0 = fmaxf(acc0[2 * h] * s0 + b0, 0.f);
    const float a1 = fmaxf(acc0[2 * h + 1] * s1 + b1, 0.f);
    const float c0 = fmaxf(acc1[2 * h] * s0 + b0, 0.f);
    const float c1 = fmaxf(acc1[2 * h + 1] * s1 + b1, 0.f);
    pk0[h] = (unsigned)f2bf(a0) | ((unsigned)f2bf(a1) << 16);
    pk1[h] = (unsigned)f2bf(c0) | ((unsigned)f2bf(c1) << 16);
  }
  *(uint4*)(y + p0 * 32 + oc0) = make_uint4(pk0[0], pk0[1], pk0[2], pk0[3]);
  *(uint4*)(y + (p0 + 1) * 32 + oc0) = make_uint4(pk1[0], pk1[1], pk1[2], pk1[3]);
}

// ---------------------------------------------------------------- halo conv
// NHWC bf16 in/out. Block = 8(oh) x 16(ow) output tile of one image x BN=64
// output channels. Input patch staged in LDS ONCE (seg-major
// [ch/8][ph][pw][8] so each MFMA A-frag is one conflict-free ds_read_b128);
// full ternary B tile staged once. Zero barriers inside the 9-tap compute
// loop. For STRIDE=2, patch columns stored parity-split (even iw then odd)
// so A-reads keep 16B lane stride (else 4-way bank conflicts).
// CIN=64 processed as two ic-halves (patch+B restage, 3 barriers total).
template <int CIN, int COUT, int STRIDE, int H, int W, int OH, int OW>
__global__ __launch_bounds__(256) void conv_halo(
    const unsigned short* __restrict__ xin,
    const unsigned short* __restrict__ bp,
    const float* __restrict__ scale, const float* __restrict__ bias,
    unsigned short* __restrict__ yout) {
  constexpr int TOH = 8, TOW = 16, BN = 64;
  constexpr int PH = (TOH - 1) * STRIDE + 3;       // 10 (s1) / 17 (s2)
  constexpr int PW = (TOW - 1) * STRIDE + 3;       // 18 / 33
  constexpr int HALF = (PW + 1) / 2;               // 17 for s2
  constexpr int PWS = (STRIDE == 2) ? 2 * HALF : PW;  // 18 / 34
  constexpr int NH = CIN / 32;                     // ic-halves
  constexpr int NKG = CIN / 8;                     // kg per tap in bp
  constexpr int TILES_W = (OW + TOW - 1) / TOW;

  __shared__ unsigned short patch[4 * PH * PWS * 8];
  __shared__ unsigned short Bb[2304 * 8];          // 36 kg x 64 n x 16B

  const int t = threadIdx.x;
  const int img = blockIdx.z;
  const int toh = blockIdx.x / TILES_W, tow = blockIdx.x % TILES_W;
  const int n0 = blockIdx.y * BN;
  const int wave = t >> 6, lane = t & 63, quad = lane >> 4, l16 = lane & 15;
  const int oh0 = toh * TOH, ow0 = tow * TOW;

  floatx4 acc[2][4];
#pragma unroll
  for (int mf = 0; mf < 2; ++mf)
#pragma unroll
    for (int nf = 0; nf < 4; ++nf) acc[mf][nf] = (floatx4){0.f, 0.f, 0.f, 0.f};

  for (int h = 0; h < NH; ++h) {
    if (h) __syncthreads();  // previous half's reads done before restage
    // ---- stage B half: 36 local kg x 64 n cells of 16B
    for (int c = t; c < 2304; c += 256) {
      const int kgl = c >> 6, n = c & 63;
      const int tap = kgl >> 2, q = kgl & 3;
      const int kg = tap * NKG + h * 4 + q;
      *(uint4*)(&Bb[c * 8]) = *(const uint4*)(bp + ((size_t)kg * COUT + n0 + n) * 8);
    }
    // ---- stage patch: PH*PW pixels x 4 ch-segs of 16B
    for (int c = t; c < PH * PW * 4; c += 256) {
      const int pix = c >> 2, seg = c & 3;
      const int pi = pix / PW, pj = pix % PW;
      const int ih = oh0 * STRIDE - 1 + pi;
      const int iw = ow0 * STRIDE - 1 + pj;
      uint4 v = make_uint4(0u, 0u, 0u, 0u);
      if ((unsigned)ih < (unsigned)H && (unsigned)iw < (unsigned)W)
        v = *(const uint4*)(xin + (((size_t)img * H + ih) * W + iw) * CIN +
                            h * 32 + seg * 8);
      const int slot = (STRIDE == 2) ? ((pj >> 1) + (pj & 1) * HALF) : pj;
      *(uint4*)(&patch[((seg * PH + pi) * PWS + slot) * 8]) = v;
    }
    __syncthreads();
    // ---- 9 taps, no barriers: pure ds_read + MFMA
#pragma unroll
    for (int tap = 0; tap < 9; ++tap) {
      const int kh = tap / 3, kw = tap % 3;
      short8 bfr[4];
#pragma unroll
      for (int nf = 0; nf < 4; ++nf)
        bfr[nf] = *(const short8*)(&Bb[(((tap * 4 + quad) << 6) + nf * 16 + l16) * 8]);
#pragma unroll
      for (int mf = 0; mf < 2; ++mf) {
        const int pi = (wave * 2 + mf) * STRIDE + kh;
        const int slot = (STRIDE == 2) ? (l16 + (kw >> 1) + (kw & 1) * HALF)
                                       : (l16 + kw);
        const short8 a = *(const short8*)(&patch[((quad * PH + pi) * PWS + slot) * 8]);
#pragma unroll
        for (int nf = 0; nf < 4; ++nf)
          acc[mf][nf] = __builtin_amdgcn_mfma_f32_16x16x32_bf16(
              a, bfr[nf], acc[mf][nf], 0, 0, 0);
      }
    }
  }

  // ---- epilogue: BN + ReLU, bf16 NHWC store
  float sc[4], bs[4];
#pragma unroll
  for (int nf = 0; nf < 4; ++nf) {
    sc[nf] = scale[n0 + nf * 16 + l16];
    bs[nf] = bias[n0 + nf * 16 + l16];
  }
#pragma unroll
  for (int mf = 0; mf < 2; ++mf) {
    const int oh = oh0 + wave * 2 + mf;
#pragma unroll
    for (int r = 0; r < 4; ++r) {
      const int ow = ow0 + quad * 4 + r;
      if ((OW % TOW == 0) || ow < OW) {
        const size_t base = (((size_t)img * OH + oh) * OW + ow) * COUT + n0;
#pragma unroll
        for (int nf = 0; nf < 4; ++nf) {
          const float vv = fmaxf(acc[mf][nf][r] * sc[nf] + bs[nf], 0.f);
          yout[base + nf * 16 + l16] = f2bf(vv);
        }
      }
    }
  }
}

// ---------------------------------------------------------------- pool (NHWC)
__global__ __launch_bounds__(256) void pool_part(
    const unsigned short* __restrict__ a, float* __restrict__ part) {
  __shared__ float sm[256];
  const int n = blockIdx.x, j = blockIdx.y, t = threadIdx.x;
  const int c = t & 127, h = t >> 7;
  const unsigned short* p = a + (size_t)n * 3136 * 128;
  float s = 0.f;
  for (int px = j * 784 + h; px < (j + 1) * 784; px += 2)
    s += bf2f(p[(size_t)px * 128 + c]);
  sm[t] = s;
  __syncthreads();
  if (t < 128) part[((size_t)n * 4 + j) * 128 + t] = sm[t] + sm[t + 128];
}

__global__ void pool_final(const float* __restrict__ part,
                           float* __restrict__ pooled) {
  const int idx = blockIdx.x * 256 + threadIdx.x;
  if (idx >= 64 * 128) return;
  const int n = idx >> 7, c = idx & 127;
  float s = 0.f;
#pragma unroll
  for (int j = 0; j < 4; ++j) s += part[((size_t)n * 4 + j) * 128 + c];
  pooled[idx] = s * (1.f / 3136.f);
}

// ---------------------------------------------------------------- linear
__global__ void linear_kernel(const float* __restrict__ pooled,
                              const float* __restrict__ ql,
                              const float* __restrict__ bl,
                              float* __restrict__ out) {
  const int idx = blockIdx.x * blockDim.x + threadIdx.x;
  if (idx >= 64 * 10) return;
  const int n = idx / 10, o = idx % 10;
  const float* p = pooled + (size_t)n * 128;
  const float* w = ql + (size_t)o * 128;
  float s = 0.f;
#pragma unroll 4
  for (int c = 0; c < 128; ++c) s += p[c] * w[c];
  out[idx] = s + bl[o];
}

// ---------------------------------------------------------------- launch
extern "C" void kernel_launch(void* const* d_in, const int* in_sizes, int n_in,
                              void* d_out, int out_size, void* d_ws,
                              size_t ws_size, hipStream_t stream) {
  const float* x  = (const float*)d_in[0];
  const float* w1 = (const float*)d_in[1];
  const float* g1 = (const float*)d_in[2];
  const float* b1 = (const float*)d_in[3];
  const float* m1 = (const float*)d_in[4];
  const float* v1 = (const float*)d_in[5];
  const float* w2 = (const float*)d_in[6];
  const float* g2 = (const float*)d_in[7];
  const float* b2 = (const float*)d_in[8];
  const float* m2 = (const float*)d_in[9];
  const float* v2 = (const float*)d_in[10];
  const float* w3 = (const float*)d_in[11];
  const float* g3 = (const float*)d_in[12];
  const float* b3 = (const float*)d_in[13];
  const float* m3 = (const float*)d_in[14];
  const float* v3 = (const float*)d_in[15];
  const float* wl = (const float*)d_in[16];
  const float* bl = (const float*)d_in[17];
  float* out = (float*)d_out;

  // ---- workspace layout ----
  float* Wf = (float*)d_ws;
  float* red = Wf;                // 16 (4 tensors x {sum, cnt, asum, pad})
  float* q1 = red + 16;           // 864
  float* ql = q1 + 864;           // 1280
  float* s1 = ql + 1280;  float* bb1 = s1 + 32;
  float* s2 = bb1 + 32;   float* bb2 = s2 + 64;
  float* s3 = bb2 + 64;   float* bb3 = s3 + 128;
  float* pooled = bb3 + 128;      // 8192
  float* part = pooled + 8192;    // 64*4*128 = 32768
  unsigned short* Us = (unsigned short*)(part + 32768);
  unsigned short* bp2 = Us;                 // 288*64   = 18432
  unsigned short* bp3 = bp2 + 18432;        // 576*128  = 73728
  unsigned short* act1 = bp3 + 73728;       // 64*12544*32 = 25690112
  unsigned short* act2 = act1 + 25690112;   // 64*12544*64 = 51380224
  unsigned short* act3 = act1;              // act1 dead after conv2: alias
  // total ~155 MB < ws_size

  // ---- ternarize (grid-parallel, 3 phases over all 4 tensors) ----
  hipMemsetAsync(red, 0, 16 * sizeof(float), stream);
  tern_phase1<<<dim3(288, 4), 256, 0, stream>>>(w1, w2, w3, wl, 864, 18432,
                                                73728, 1280, red);
  tern_phase2<<<dim3(288, 4), 256, 0, stream>>>(w1, w2, w3, wl, 864, 18432,
                                                73728, 1280, red);
  tern_phase3<<<dim3(5, 2), 256, 0, stream>>>(w1, wl, 864, 1280, q1, ql, red);

  bnfold_all<<<1, 256, 0, stream>>>(g1, b1, m1, v1, g2, b2, m2, v2, g3, b3,
                                    m3, v3, s1, bb1, s2, bb2, s3, bb3, red);
  pack_weights<32, 64><<<72, 256, 0, stream>>>(w2, red + 4, bp2);
  pack_weights<64, 128><<<288, 256, 0, stream>>>(w3, red + 8, bp3);

  // ---- network ----
  conv1_bn_relu<<<dim3(25, 4, 64), 256, 0, stream>>>(x, q1, s1, bb1, act1);
  // conv2: 112x112 out -> 14x7 tiles of 8x16, one n-block of 64
  conv_halo<32, 64, 1, 112, 112, 112, 112>
      <<<dim3(98, 1, 64), 256, 0, stream>>>(act1, bp2, s2, bb2, act2);
  // conv3: 56x56 out -> 7x4 tiles (last ow-tile partial), 2 n-blocks of 64
  conv_halo<64, 128, 2, 112, 112, 56, 56>
      <<<dim3(28, 2, 64), 256, 0, stream>>>(act2, bp3, s3, bb3, act3);
  pool_part<<<dim3(64, 4), 256, 0, stream>>>(act3, part);
  pool_final<<<32, 256, 0, stream>>>(part, pooled);
  linear_kernel<<<3, 256, 0, stream>>>(pooled, ql, bl, out);
}

// Round 6
// 441.181 us; speedup vs baseline: 5.2989x; 1.1009x over previous
//
#include <hip/hip_runtime.h>
#include <cstddef>

typedef __attribute__((ext_vector_type(8))) short short8;
typedef __attribute__((ext_vector_type(4))) float floatx4;

// ---------------------------------------------------------------- bf16 utils
__device__ __forceinline__ unsigned short f2bf(float f) {
  union { float f; unsigned u; } v; v.f = f;
  const unsigned r = v.u + 0x7fffu + ((v.u >> 16) & 1u);  // RNE
  return (unsigned short)(r >> 16);
}
__device__ __forceinline__ float bf2f(unsigned short u) {
  union { unsigned u; float f; } v; v.u = ((unsigned)u) << 16;
  return v.f;
}

// ---------------------------------------------------------------- reductions
__device__ __forceinline__ float block_reduce_sum(float v, float* sm) {
#pragma unroll
  for (int off = 32; off > 0; off >>= 1) v += __shfl_down(v, off, 64);
  const int lane = threadIdx.x & 63, wid = threadIdx.x >> 6;
  __syncthreads();
  if (lane == 0) sm[wid] = v;
  __syncthreads();
  if (threadIdx.x == 0) {
    float t = 0.f;
    const int nw = (blockDim.x + 63) >> 6;
    for (int i = 0; i < nw; ++i) t += sm[i];
    sm[0] = t;
  }
  __syncthreads();
  return sm[0];
}

// ---------------------------------------------------------------- ternarize
// Grid-parallel 3-phase TWN over all 4 weight tensors at once.
// red[t*4+0]=sum|w|, red[t*4+1]=masked count, red[t*4+2]=masked sum|w|.
__device__ __forceinline__ void tsel(int t, const float* w0, const float* w1,
                                     const float* w2, const float* w3, int n0,
                                     int n1, int n2, int n3,
                                     const float*& w, int& n) {
  w = (t == 0) ? w0 : (t == 1) ? w1 : (t == 2) ? w2 : w3;
  n = (t == 0) ? n0 : (t == 1) ? n1 : (t == 2) ? n2 : n3;
}

__global__ __launch_bounds__(256) void tern_phase1(
    const float* w0, const float* w1, const float* w2, const float* w3,
    int n0, int n1, int n2, int n3, float* __restrict__ red) {
  __shared__ float sm[8];
  const float* w; int n;
  tsel(blockIdx.y, w0, w1, w2, w3, n0, n1, n2, n3, w, n);
  if ((int)blockIdx.x * 256 >= n) return;
  const int i = blockIdx.x * 256 + threadIdx.x;
  float s = (i < n) ? fabsf(w[i]) : 0.f;
  s = block_reduce_sum(s, sm);
  if (threadIdx.x == 0) atomicAdd(&red[blockIdx.y * 4 + 0], s);
}

__global__ __launch_bounds__(256) void tern_phase2(
    const float* w0, const float* w1, const float* w2, const float* w3,
    int n0, int n1, int n2, int n3, float* __restrict__ red) {
  __shared__ float sm[8];
  const float* w; int n;
  tsel(blockIdx.y, w0, w1, w2, w3, n0, n1, n2, n3, w, n);
  if ((int)blockIdx.x * 256 >= n) return;
  const float delta = 0.7f * red[blockIdx.y * 4 + 0] / (float)n;
  const int i = blockIdx.x * 256 + threadIdx.x;
  float c = 0.f, a = 0.f;
  if (i < n) {
    const float v = fabsf(w[i]);
    if (v > delta) { c = 1.f; a = v; }
  }
  c = block_reduce_sum(c, sm);
  a = block_reduce_sum(a, sm);
  if (threadIdx.x == 0) {
    atomicAdd(&red[blockIdx.y * 4 + 1], c);
    atomicAdd(&red[blockIdx.y * 4 + 2], a);
  }
}

// Materialize q (fp32 +/-alpha / 0) only for w1 (t=0) and wl (t=1 -> wl).
__global__ __launch_bounds__(256) void tern_phase3(
    const float* __restrict__ wa, const float* __restrict__ wb, int na, int nb,
    float* __restrict__ qa, float* __restrict__ qb,
    const float* __restrict__ red) {
  const int t = blockIdx.y;                    // 0 -> w1, 1 -> wl
  const float* w = t ? wb : wa;
  float* q = t ? qb : qa;
  const int n = t ? nb : na;
  const int rb = t ? 12 : 0;
  const float delta = 0.7f * red[rb + 0] / (float)n;
  const float alpha = red[rb + 2] / fmaxf(red[rb + 1], 1.f);
  const int i = blockIdx.x * 256 + threadIdx.x;
  if (i < n) {
    const float wi = w[i];
    q[i] = (fabsf(wi) > delta) ? copysignf(alpha, wi) : 0.f;
  }
}

// ---------------------------------------------------------------- BN fold
__global__ void bnfold_all(
    const float* g1, const float* b1, const float* m1, const float* v1,
    const float* g2, const float* b2, const float* m2, const float* v2,
    const float* g3, const float* b3, const float* m3, const float* v3,
    float* s1, float* bb1, float* s2, float* bb2, float* s3, float* bb3,
    const float* __restrict__ red) {
  const int i = threadIdx.x;
  if (i < 32) {
    const float inv = g1[i] / sqrtf(v1[i] + 1e-5f);
    s1[i] = inv; bb1[i] = b1[i] - m1[i] * inv;
  } else if (i < 96) {
    const int c = i - 32;
    const float inv = g2[c] / sqrtf(v2[c] + 1e-5f);
    const float a = red[6] / fmaxf(red[5], 1.f);
    s2[c] = a * inv; bb2[c] = b2[c] - m2[c] * inv;
  } else if (i < 224) {
    const int c = i - 96;
    const float inv = g3[c] / sqrtf(v3[c] + 1e-5f);
    const float a = red[10] / fmaxf(red[9], 1.f);
    s3[c] = a * inv; bb3[c] = b3[c] - m3[c] * inv;
  }
}

// ---------------------------------------------------------------- weight pack
// Original OIHW fp32 w -> sign bf16 (+1/-1/0, exact; alpha folded into BN
// scale). GEMM layout k = (kh*3+kw)*CIN + ic, stored ((k>>3)*COUT+n)*8+(k&7).
template <int CIN, int COUT>
__global__ void pack_weights(const float* __restrict__ w,
                             const float* __restrict__ red_t,
                             unsigned short* __restrict__ bp) {
  constexpr int K = CIN * 9;
  const float delta = 0.7f * red_t[0] / (float)(K * COUT);
  const int idx = blockIdx.x * 256 + threadIdx.x;
  if (idx >= K * COUT) return;
  const int k = idx / COUT, n = idx % COUT;
  const int tap = k / CIN, ic = k % CIN;
  const int kh = tap / 3, kw = tap % 3;
  const float v = w[(((size_t)n * CIN + ic) * 3 + kh) * 3 + kw];
  const unsigned short sgn = (v > delta) ? 0x3F80u : (v < -delta ? 0xBF80u : 0u);
  bp[((size_t)(k >> 3) * COUT + n) * 8 + (k & 7)] = sgn;
}

// ---------------------------------------------------------------- conv1
__global__ __launch_bounds__(256) void conv1_bn_relu(
    const float* __restrict__ x, const float* __restrict__ q,
    const float* __restrict__ scale, const float* __restrict__ bias,
    unsigned short* __restrict__ y) {
  __shared__ float wsm[8 * 27];
  const int oc0 = blockIdx.y * 8;
  for (int i = threadIdx.x; i < 8 * 27; i += 256) wsm[i] = q[oc0 * 27 + i];
  __syncthreads();
  const int s2 = blockIdx.x * 256 + threadIdx.x;  // pixel-pair id
  if (s2 >= 112 * 56) return;
  const int oh = s2 / 56, ow0 = (s2 % 56) * 2;
  float acc0[8], acc1[8];
#pragma unroll
  for (int j = 0; j < 8; ++j) { acc0[j] = 0.f; acc1[j] = 0.f; }
  const int ih0 = oh * 2 - 1, iw0 = ow0 * 2 - 1;
  const float* xn = x + (size_t)blockIdx.z * 3 * 224 * 224;
  for (int ic = 0; ic < 3; ++ic) {
    const float* xc = xn + (size_t)ic * 224 * 224;
#pragma unroll
    for (int kh = 0; kh < 3; ++kh) {
      const int ih = ih0 + kh;
      if ((unsigned)ih >= 224u) continue;
      const float* xr = xc + (size_t)ih * 224;
      float c[5];
#pragma unroll
      for (int j = 0; j < 5; ++j) {
        const int iw = iw0 + j;
        c[j] = ((unsigned)iw < 224u) ? xr[iw] : 0.f;
      }
#pragma unroll
      for (int kw = 0; kw < 3; ++kw) {
        const int wi = ic * 9 + kh * 3 + kw;
#pragma unroll
        for (int j = 0; j < 8; ++j) {
          const float wv = wsm[j * 27 + wi];
          acc0[j] += c[kw] * wv;
          acc1[j] += c[kw + 2] * wv;
        }
      }
    }
  }
  const size_t p0 = (size_t)blockIdx.z * 12544 + (size_t)oh * 112 + ow0;
  unsigned pk0[4], pk1[4];
#pragma unroll
  for (int h = 0; h < 4; ++h) {
    const float s0 = scale[oc0 + 2 * h], s1 = scale[oc0 + 2 * h + 1];
    const float b0 = bias[oc0 + 2 * h], b1 = bias[oc0 + 2 * h + 1];
    const float a0 = fmaxf(acc0[2 * h] * s0 + b0, 0.f);
    const float a1 = fmaxf(acc0[2 * h + 1] * s1 + b1, 0.f);
    const float c0 = fmaxf(acc1[2 * h] * s0 + b0, 0.f);
    const float c1 = fmaxf(acc1[2 * h + 1] * s1 + b1, 0.f);
    pk0[h] = (unsigned)f2bf(a0) | ((unsigned)f2bf(a1) << 16);
    pk1[h] = (unsigned)f2bf(c0) | ((unsigned)f2bf(c1) << 16);
  }
  *(uint4*)(y + p0 * 32 + oc0) = make_uint4(pk0[0], pk0[1], pk0[2], pk0[3]);
  *(uint4*)(y + (p0 + 1) * 32 + oc0) = make_uint4(pk1[0], pk1[1], pk1[2], pk1[3]);
}

// ---------------------------------------------------------------- halo conv v2
// NHWC bf16 in/out. Block = 8x16 output tile of one image x ALL COUT channels.
// Patch staged in LDS once per ic-half (seg-major: A-frag = one conflict-free
// ds_read_b128; stride-2 uses parity-split columns). B fragments NEVER touch
// LDS: each lane global-loads its 16B frag from the packed (k-inner-8) weight
// buffer (L2-hot, 144KB max), software-prefetched one tap ahead. Barriers:
// 1 per block (CIN=32) / 3 (CIN=64). Wave layout: MWAVES waves along M
// (MF=8/MWAVES frags), 4/MWAVES along N (NF frags each).
template <int CIN, int COUT, int STRIDE, int H, int W, int OH, int OW,
          int MWAVES>
__global__ __launch_bounds__(256) void conv_halo2(
    const unsigned short* __restrict__ xin,
    const unsigned short* __restrict__ bp,
    const float* __restrict__ scale, const float* __restrict__ bias,
    unsigned short* __restrict__ yout) {
  constexpr int TOH = 8, TOW = 16;
  constexpr int PH = (TOH - 1) * STRIDE + 3;       // 10 (s1) / 17 (s2)
  constexpr int PW = (TOW - 1) * STRIDE + 3;       // 18 / 33
  constexpr int HALF = (PW + 1) / 2;               // 17 for s2
  constexpr int PWS = (STRIDE == 2) ? 2 * HALF : PW;  // 18 / 34
  constexpr int NH = CIN / 32;                     // ic-halves
  constexpr int NKG = CIN / 8;                     // k-groups per tap in bp
  constexpr int TILES_W = (OW + TOW - 1) / TOW;
  constexpr int NWN = 4 / MWAVES;                  // waves along N
  constexpr int MF = 8 / MWAVES;                   // M frags per wave
  constexpr int NF = COUT / (16 * NWN);            // N frags per wave

  __shared__ unsigned short patch[4 * PH * PWS * 8];

  const int t = threadIdx.x;
  const int img = blockIdx.z;
  const int toh = blockIdx.x / TILES_W, tow = blockIdx.x % TILES_W;
  const int wave = t >> 6, lane = t & 63, quad = lane >> 4, l16 = lane & 15;
  const int mw = wave % MWAVES, nh = wave / MWAVES;
  const int oh0 = toh * TOH, ow0 = tow * TOW;
  const int nwb = nh * (COUT / NWN);

  auto stage = [&](int h) {
    for (int c = t; c < PH * PW * 4; c += 256) {
      const int pix = c >> 2, seg = c & 3;
      const int pi = pix / PW, pj = pix % PW;
      const int ih = oh0 * STRIDE - 1 + pi;
      const int iw = ow0 * STRIDE - 1 + pj;
      uint4 v = make_uint4(0u, 0u, 0u, 0u);
      if ((unsigned)ih < (unsigned)H && (unsigned)iw < (unsigned)W)
        v = *(const uint4*)(xin + (((size_t)img * H + ih) * W + iw) * CIN +
                            h * 32 + seg * 8);
      const int slot = (STRIDE == 2) ? ((pj >> 1) + (pj & 1) * HALF) : pj;
      *(uint4*)(&patch[((seg * PH + pi) * PWS + slot) * 8]) = v;
    }
  };

  floatx4 acc[MF][NF];
#pragma unroll
  for (int mf = 0; mf < MF; ++mf)
#pragma unroll
    for (int nf = 0; nf < NF; ++nf) acc[mf][nf] = (floatx4){0.f, 0.f, 0.f, 0.f};

  stage(0);
  short8 bcur[NF], bnxt[NF];
  // prefetch B for it=0: kg = tap0*NKG + h0*4 + quad = quad
#pragma unroll
  for (int nf = 0; nf < NF; ++nf)
    bcur[nf] = *(const short8*)(bp +
        ((size_t)quad * COUT + nwb + nf * 16 + l16) * 8);
  __syncthreads();

#pragma unroll
  for (int it = 0; it < NH * 9; ++it) {
    const int tap = it % 9;
    const int kh = tap / 3, kw = tap % 3;
    if (NH == 2 && it == 9) {
      __syncthreads();   // all waves done reading half 0
      stage(1);
      __syncthreads();
    }
    if (it + 1 < NH * 9) {
      const int h2 = (it + 1) / 9, tap2 = (it + 1) % 9;
      const int kg = tap2 * NKG + h2 * 4 + quad;
#pragma unroll
      for (int nf = 0; nf < NF; ++nf)
        bnxt[nf] = *(const short8*)(bp +
            ((size_t)kg * COUT + nwb + nf * 16 + l16) * 8);
    }
#pragma unroll
    for (int mf = 0; mf < MF; ++mf) {
      const int pi = (mw * MF + mf) * STRIDE + kh;
      const int slot = (STRIDE == 2) ? (l16 + (kw >> 1) + (kw & 1) * HALF)
                                     : (l16 + kw);
      const short8 a =
          *(const short8*)(&patch[((quad * PH + pi) * PWS + slot) * 8]);
#pragma unroll
      for (int nf = 0; nf < NF; ++nf)
        acc[mf][nf] = __builtin_amdgcn_mfma_f32_16x16x32_bf16(
            a, bcur[nf], acc[mf][nf], 0, 0, 0);
    }
#pragma unroll
    for (int nf = 0; nf < NF; ++nf) bcur[nf] = bnxt[nf];
  }

  // ---- epilogue: BN + ReLU, bf16 NHWC store
  float sc[NF], bs[NF];
#pragma unroll
  for (int nf = 0; nf < NF; ++nf) {
    sc[nf] = scale[nwb + nf * 16 + l16];
    bs[nf] = bias[nwb + nf * 16 + l16];
  }
#pragma unroll
  for (int mf = 0; mf < MF; ++mf) {
    const int oh = oh0 + mw * MF + mf;
#pragma unroll
    for (int r = 0; r < 4; ++r) {
      const int ow = ow0 + quad * 4 + r;
      if ((OW % TOW == 0) || ow < OW) {
        const size_t base = (((size_t)img * OH + oh) * OW + ow) * COUT + nwb;
#pragma unroll
        for (int nf = 0; nf < NF; ++nf) {
          const float vv = fmaxf(acc[mf][nf][r] * sc[nf] + bs[nf], 0.f);
          yout[base + nf * 16 + l16] = f2bf(vv);
        }
      }
    }
  }
}

// ---------------------------------------------------------------- pool (NHWC)
__global__ __launch_bounds__(256) void pool_part(
    const unsigned short* __restrict__ a, float* __restrict__ part) {
  __shared__ float sm[256];
  const int n = blockIdx.x, j = blockIdx.y, t = threadIdx.x;
  const int c = t & 127, h = t >> 7;
  const unsigned short* p = a + (size_t)n * 3136 * 128;
  float s = 0.f;
  for (int px = j * 784 + h; px < (j + 1) * 784; px += 2)
    s += bf2f(p[(size_t)px * 128 + c]);
  sm[t] = s;
  __syncthreads();
  if (t < 128) part[((size_t)n * 4 + j) * 128 + t] = sm[t] + sm[t + 128];
}

__global__ void pool_final(const float* __restrict__ part,
                           float* __restrict__ pooled) {
  const int idx = blockIdx.x * 256 + threadIdx.x;
  if (idx >= 64 * 128) return;
  const int n = idx >> 7, c = idx & 127;
  float s = 0.f;
#pragma unroll
  for (int j = 0; j < 4; ++j) s += part[((size_t)n * 4 + j) * 128 + c];
  pooled[idx] = s * (1.f / 3136.f);
}

// ---------------------------------------------------------------- linear
__global__ void linear_kernel(const float* __restrict__ pooled,
                              const float* __restrict__ ql,
                              const float* __restrict__ bl,
                              float* __restrict__ out) {
  const int idx = blockIdx.x * blockDim.x + threadIdx.x;
  if (idx >= 64 * 10) return;
  const int n = idx / 10, o = idx % 10;
  const float* p = pooled + (size_t)n * 128;
  const float* w = ql + (size_t)o * 128;
  float s = 0.f;
#pragma unroll 4
  for (int c = 0; c < 128; ++c) s += p[c] * w[c];
  out[idx] = s + bl[o];
}

// ---------------------------------------------------------------- launch
extern "C" void kernel_launch(void* const* d_in, const int* in_sizes, int n_in,
                              void* d_out, int out_size, void* d_ws,
                              size_t ws_size, hipStream_t stream) {
  const float* x  = (const float*)d_in[0];
  const float* w1 = (const float*)d_in[1];
  const float* g1 = (const float*)d_in[2];
  const float* b1 = (const float*)d_in[3];
  const float* m1 = (const float*)d_in[4];
  const float* v1 = (const float*)d_in[5];
  const float* w2 = (const float*)d_in[6];
  const float* g2 = (const float*)d_in[7];
  const float* b2 = (const float*)d_in[8];
  const float* m2 = (const float*)d_in[9];
  const float* v2 = (const float*)d_in[10];
  const float* w3 = (const float*)d_in[11];
  const float* g3 = (const float*)d_in[12];
  const float* b3 = (const float*)d_in[13];
  const float* m3 = (const float*)d_in[14];
  const float* v3 = (const float*)d_in[15];
  const float* wl = (const float*)d_in[16];
  const float* bl = (const float*)d_in[17];
  float* out = (float*)d_out;

  // ---- workspace layout ----
  float* Wf = (float*)d_ws;
  float* red = Wf;                // 16 (4 tensors x {sum, cnt, asum, pad})
  float* q1 = red + 16;           // 864
  float* ql = q1 + 864;           // 1280
  float* s1 = ql + 1280;  float* bb1 = s1 + 32;
  float* s2 = bb1 + 32;   float* bb2 = s2 + 64;
  float* s3 = bb2 + 64;   float* bb3 = s3 + 128;
  float* pooled = bb3 + 128;      // 8192
  float* part = pooled + 8192;    // 64*4*128 = 32768
  unsigned short* Us = (unsigned short*)(part + 32768);
  unsigned short* bp2 = Us;                 // 288*64   = 18432
  unsigned short* bp3 = bp2 + 18432;        // 576*128  = 73728
  unsigned short* act1 = bp3 + 73728;       // 64*12544*32 = 25690112
  unsigned short* act2 = act1 + 25690112;   // 64*12544*64 = 51380224
  unsigned short* act3 = act1;              // act1 dead after conv2: alias
  // total ~155 MB < ws_size

  // ---- ternarize (grid-parallel, 3 phases over all 4 tensors) ----
  hipMemsetAsync(red, 0, 16 * sizeof(float), stream);
  tern_phase1<<<dim3(288, 4), 256, 0, stream>>>(w1, w2, w3, wl, 864, 18432,
                                                73728, 1280, red);
  tern_phase2<<<dim3(288, 4), 256, 0, stream>>>(w1, w2, w3, wl, 864, 18432,
                                                73728, 1280, red);
  tern_phase3<<<dim3(5, 2), 256, 0, stream>>>(w1, wl, 864, 1280, q1, ql, red);

  bnfold_all<<<1, 256, 0, stream>>>(g1, b1, m1, v1, g2, b2, m2, v2, g3, b3,
                                    m3, v3, s1, bb1, s2, bb2, s3, bb3, red);
  pack_weights<32, 64><<<72, 256, 0, stream>>>(w2, red + 4, bp2);
  pack_weights<64, 128><<<288, 256, 0, stream>>>(w3, red + 8, bp3);

  // ---- network ----
  conv1_bn_relu<<<dim3(25, 4, 64), 256, 0, stream>>>(x, q1, s1, bb1, act1);
  // conv2: 14x7 tiles of 8x16, COUT=64, 4 waves along M
  conv_halo2<32, 64, 1, 112, 112, 112, 112, 4>
      <<<dim3(98, 1, 64), 256, 0, stream>>>(act1, bp2, s2, bb2, act2);
  // conv3: 7x4 tiles (last ow-tile partial), COUT=128 merged, 2x2 wave grid
  conv_halo2<64, 128, 2, 112, 112, 56, 56, 2>
      <<<dim3(28, 1, 64), 256, 0, stream>>>(act2, bp3, s3, bb3, act3);
  pool_part<<<dim3(64, 4), 256, 0, stream>>>(act3, part);
  pool_final<<<32, 256, 0, stream>>>(part, pooled);
  linear_kernel<<<3, 256, 0, stream>>>(pooled, ql, bl, out);
}

// Round 7
// 293.207 us; speedup vs baseline: 7.9731x; 1.5047x over previous
//
#include <hip/hip_runtime.h>
#include <cstddef>

typedef __attribute__((ext_vector_type(8))) short short8;
typedef __attribute__((ext_vector_type(4))) float floatx4;

// ---------------------------------------------------------------- bf16 utils
__device__ __forceinline__ unsigned short f2bf(float f) {
  union { float f; unsigned u; } v; v.f = f;
  const unsigned r = v.u + 0x7fffu + ((v.u >> 16) & 1u);  // RNE
  return (unsigned short)(r >> 16);
}

// ---------------------------------------------------------------- reductions
__device__ __forceinline__ float block_reduce_sum(float v, float* sm) {
#pragma unroll
  for (int off = 32; off > 0; off >>= 1) v += __shfl_down(v, off, 64);
  const int lane = threadIdx.x & 63, wid = threadIdx.x >> 6;
  __syncthreads();
  if (lane == 0) sm[wid] = v;
  __syncthreads();
  if (threadIdx.x == 0) {
    float t = 0.f;
    const int nw = (blockDim.x + 63) >> 6;
    for (int i = 0; i < nw; ++i) t += sm[i];
    sm[0] = t;
  }
  __syncthreads();
  return sm[0];
}

// ---------------------------------------------------------------- ternarize
// Grid-parallel 3-phase TWN over all 4 weight tensors at once.
// red[t*4+0]=sum|w|, red[t*4+1]=masked count, red[t*4+2]=masked sum|w|.
__device__ __forceinline__ void tsel(int t, const float* w0, const float* w1,
                                     const float* w2, const float* w3, int n0,
                                     int n1, int n2, int n3,
                                     const float*& w, int& n) {
  w = (t == 0) ? w0 : (t == 1) ? w1 : (t == 2) ? w2 : w3;
  n = (t == 0) ? n0 : (t == 1) ? n1 : (t == 2) ? n2 : n3;
}

__global__ __launch_bounds__(256) void tern_phase1(
    const float* w0, const float* w1, const float* w2, const float* w3,
    int n0, int n1, int n2, int n3, float* __restrict__ red) {
  __shared__ float sm[8];
  const float* w; int n;
  tsel(blockIdx.y, w0, w1, w2, w3, n0, n1, n2, n3, w, n);
  if ((int)blockIdx.x * 256 >= n) return;
  const int i = blockIdx.x * 256 + threadIdx.x;
  float s = (i < n) ? fabsf(w[i]) : 0.f;
  s = block_reduce_sum(s, sm);
  if (threadIdx.x == 0) atomicAdd(&red[blockIdx.y * 4 + 0], s);
}

__global__ __launch_bounds__(256) void tern_phase2(
    const float* w0, const float* w1, const float* w2, const float* w3,
    int n0, int n1, int n2, int n3, float* __restrict__ red) {
  __shared__ float sm[8];
  const float* w; int n;
  tsel(blockIdx.y, w0, w1, w2, w3, n0, n1, n2, n3, w, n);
  if ((int)blockIdx.x * 256 >= n) return;
  const float delta = 0.7f * red[blockIdx.y * 4 + 0] / (float)n;
  const int i = blockIdx.x * 256 + threadIdx.x;
  float c = 0.f, a = 0.f;
  if (i < n) {
    const float v = fabsf(w[i]);
    if (v > delta) { c = 1.f; a = v; }
  }
  c = block_reduce_sum(c, sm);
  a = block_reduce_sum(a, sm);
  if (threadIdx.x == 0) {
    atomicAdd(&red[blockIdx.y * 4 + 1], c);
    atomicAdd(&red[blockIdx.y * 4 + 2], a);
  }
}

// Materialize fp32 q (+/-alpha / 0) for wl only (linear layer).
__global__ __launch_bounds__(256) void tern_phase3(
    const float* __restrict__ w, int n, float* __restrict__ q,
    const float* __restrict__ red) {
  const float delta = 0.7f * red[12] / (float)n;
  const float alpha = red[14] / fmaxf(red[13], 1.f);
  const int i = blockIdx.x * 256 + threadIdx.x;
  if (i < n) {
    const float wi = w[i];
    q[i] = (fabsf(wi) > delta) ? copysignf(alpha, wi) : 0.f;
  }
}

// ---------------------------------------------------------------- BN fold
// All three layers fold alpha into scale (conv kernels use sign weights).
__global__ void bnfold_all(
    const float* g1, const float* b1, const float* m1, const float* v1,
    const float* g2, const float* b2, const float* m2, const float* v2,
    const float* g3, const float* b3, const float* m3, const float* v3,
    float* s1, float* bb1, float* s2, float* bb2, float* s3, float* bb3,
    const float* __restrict__ red) {
  const int i = threadIdx.x;
  if (i < 32) {
    const float inv = g1[i] / sqrtf(v1[i] + 1e-5f);
    const float a = red[2] / fmaxf(red[1], 1.f);
    s1[i] = a * inv; bb1[i] = b1[i] - m1[i] * inv;
  } else if (i < 96) {
    const int c = i - 32;
    const float inv = g2[c] / sqrtf(v2[c] + 1e-5f);
    const float a = red[6] / fmaxf(red[5], 1.f);
    s2[c] = a * inv; bb2[c] = b2[c] - m2[c] * inv;
  } else if (i < 224) {
    const int c = i - 96;
    const float inv = g3[c] / sqrtf(v3[c] + 1e-5f);
    const float a = red[10] / fmaxf(red[9], 1.f);
    s3[c] = a * inv; bb3[c] = b3[c] - m3[c] * inv;
  }
}

// ---------------------------------------------------------------- weight pack
// conv2/3: OIHW fp32 -> sign bf16 (+1/-1/0), k=(kh*3+kw)*CIN+ic, stored
// ((k>>3)*COUT+n)*8+(k&7) so a lane's B-frag is one 16B global load.
template <int CIN, int COUT>
__global__ void pack_weights(const float* __restrict__ w,
                             const float* __restrict__ red_t,
                             unsigned short* __restrict__ bp) {
  constexpr int K = CIN * 9;
  const float delta = 0.7f * red_t[0] / (float)(K * COUT);
  const int idx = blockIdx.x * 256 + threadIdx.x;
  if (idx >= K * COUT) return;
  const int k = idx / COUT, n = idx % COUT;
  const int tap = k / CIN, ic = k % CIN;
  const int kh = tap / 3, kw = tap % 3;
  const float v = w[(((size_t)n * CIN + ic) * 3 + kh) * 3 + kw];
  const unsigned short sgn = (v > delta) ? 0x3F80u : (v < -delta ? 0xBF80u : 0u);
  bp[((size_t)(k >> 3) * COUT + n) * 8 + (k & 7)] = sgn;
}

// conv1: OIHW [32][3][3][3] -> tap-major fp32 signs q1t[tap][oc], tap=ic*9+kh*3+kw
__global__ void pack_w1(const float* __restrict__ w,
                        const float* __restrict__ red,
                        float* __restrict__ q1t) {
  const int idx = threadIdx.x + blockIdx.x * 256;
  if (idx >= 864) return;
  const float delta = 0.7f * red[0] / 864.f;
  const int tap = idx / 32, oc = idx % 32;
  const int ic = tap / 9, kh = (tap % 9) / 3, kw = tap % 3;
  const float v = w[((oc * 3 + ic) * 3 + kh) * 3 + kw];
  q1t[idx] = (v > delta) ? 1.f : (v < -delta ? -1.f : 0.f);
}

// ---------------------------------------------------------------- conv1 v2
// Direct fp32, stride 2, pad 1, CIN=3. Block = one image x 2 output rows x
// 112 ow x all 32 oc. Input rows staged coalesced in LDS (lane stride 8B =
// free 2-way). Weights read at wave-uniform addresses from tap-major q1t ->
// scalar loads (SGPR operand FMAs, no per-FMA LDS read). One thread writes
// the full 64B NHWC pixel line -> no partial-line RMW.
__global__ __launch_bounds__(256) void conv1_v2(
    const float* __restrict__ x, const float* __restrict__ q1t,
    const float* __restrict__ scale, const float* __restrict__ bias,
    unsigned short* __restrict__ y) {
  __shared__ float xs[15 * 225];  // [ic*5 + dr][slot], slot = iw+1
  const int n = blockIdx.y;
  const int oh0 = blockIdx.x * 2;
  const int t = threadIdx.x;
  const int ih_base = oh0 * 2 - 1;
  for (int idx = t; idx < 15 * 225; idx += 256) {
    const int row = idx / 225, s = idx % 225;
    const int ic = row / 5, dr = row % 5;
    const int ih = ih_base + dr, iw = s - 1;
    float v = 0.f;
    if ((unsigned)ih < 224u && (unsigned)iw < 224u)
      v = x[((size_t)n * 3 + ic) * 50176 + (size_t)ih * 224 + iw];
    xs[idx] = v;
  }
  __syncthreads();
  if (t >= 224) return;
  const int r = t / 112, ow = t % 112;
  float acc[32];
#pragma unroll
  for (int j = 0; j < 32; ++j) acc[j] = 0.f;
#pragma unroll
  for (int ic = 0; ic < 3; ++ic)
#pragma unroll
    for (int kh = 0; kh < 3; ++kh) {
      const float* xr = &xs[(ic * 5 + r * 2 + kh) * 225 + 2 * ow];
      const float xv0 = xr[0], xv1 = xr[1], xv2 = xr[2];
#pragma unroll
      for (int kw = 0; kw < 3; ++kw) {
        const float xv = (kw == 0) ? xv0 : (kw == 1) ? xv1 : xv2;
        const float* wrow = &q1t[(ic * 9 + kh * 3 + kw) * 32];
#pragma unroll
        for (int j = 0; j < 32; ++j) acc[j] += xv * wrow[j];
      }
    }
  const int oh = oh0 + r;
  unsigned pk[16];
#pragma unroll
  for (int h = 0; h < 16; ++h) {
    const float a0 = fmaxf(acc[2 * h] * scale[2 * h] + bias[2 * h], 0.f);
    const float a1 = fmaxf(acc[2 * h + 1] * scale[2 * h + 1] + bias[2 * h + 1], 0.f);
    pk[h] = (unsigned)f2bf(a0) | ((unsigned)f2bf(a1) << 16);
  }
  unsigned short* dst = y + (((size_t)n * 112 + oh) * 112 + ow) * 32;
#pragma unroll
  for (int v = 0; v < 4; ++v)
    *(uint4*)(dst + v * 8) = make_uint4(pk[4 * v], pk[4 * v + 1],
                                        pk[4 * v + 2], pk[4 * v + 3]);
}

// ---------------------------------------------------------------- halo conv v2
// NHWC bf16 in. Block = 8x16 output tile of one image x ALL COUT channels.
// Patch staged in LDS once per ic-half; B frags global-loaded (L2-hot),
// prefetched one tap ahead. POOL=1: instead of storing the activation,
// accumulate relu'd fp32 per-channel tile sums into pooled[img][ch] via
// shfl quad-reduction + one atomicAdd per (wave, channel) -> act3 never hits
// memory.
template <int CIN, int COUT, int STRIDE, int H, int W, int OH, int OW,
          int MWAVES, int POOL>
__global__ __launch_bounds__(256) void conv_halo2(
    const unsigned short* __restrict__ xin,
    const unsigned short* __restrict__ bp,
    const float* __restrict__ scale, const float* __restrict__ bias,
    unsigned short* __restrict__ yout, float* __restrict__ pooled) {
  constexpr int TOH = 8, TOW = 16;
  constexpr int PH = (TOH - 1) * STRIDE + 3;
  constexpr int PW = (TOW - 1) * STRIDE + 3;
  constexpr int HALF = (PW + 1) / 2;
  constexpr int PWS = (STRIDE == 2) ? 2 * HALF : PW;
  constexpr int NH = CIN / 32;
  constexpr int NKG = CIN / 8;
  constexpr int TILES_W = (OW + TOW - 1) / TOW;
  constexpr int NWN = 4 / MWAVES;
  constexpr int MF = 8 / MWAVES;
  constexpr int NF = COUT / (16 * NWN);

  __shared__ unsigned short patch[4 * PH * PWS * 8];

  const int t = threadIdx.x;
  const int img = blockIdx.z;
  const int toh = blockIdx.x / TILES_W, tow = blockIdx.x % TILES_W;
  const int wave = t >> 6, lane = t & 63, quad = lane >> 4, l16 = lane & 15;
  const int mw = wave % MWAVES, nh = wave / MWAVES;
  const int oh0 = toh * TOH, ow0 = tow * TOW;
  const int nwb = nh * (COUT / NWN);

  auto stage = [&](int h) {
    for (int c = t; c < PH * PW * 4; c += 256) {
      const int pix = c >> 2, seg = c & 3;
      const int pi = pix / PW, pj = pix % PW;
      const int ih = oh0 * STRIDE - 1 + pi;
      const int iw = ow0 * STRIDE - 1 + pj;
      uint4 v = make_uint4(0u, 0u, 0u, 0u);
      if ((unsigned)ih < (unsigned)H && (unsigned)iw < (unsigned)W)
        v = *(const uint4*)(xin + (((size_t)img * H + ih) * W + iw) * CIN +
                            h * 32 + seg * 8);
      const int slot = (STRIDE == 2) ? ((pj >> 1) + (pj & 1) * HALF) : pj;
      *(uint4*)(&patch[((seg * PH + pi) * PWS + slot) * 8]) = v;
    }
  };

  floatx4 acc[MF][NF];
#pragma unroll
  for (int mf = 0; mf < MF; ++mf)
#pragma unroll
    for (int nf = 0; nf < NF; ++nf) acc[mf][nf] = (floatx4){0.f, 0.f, 0.f, 0.f};

  stage(0);
  short8 bcur[NF], bnxt[NF];
#pragma unroll
  for (int nf = 0; nf < NF; ++nf)
    bcur[nf] = *(const short8*)(bp +
        ((size_t)quad * COUT + nwb + nf * 16 + l16) * 8);
  __syncthreads();

#pragma unroll
  for (int it = 0; it < NH * 9; ++it) {
    const int tap = it % 9;
    const int kh = tap / 3, kw = tap % 3;
    if (NH == 2 && it == 9) {
      __syncthreads();
      stage(1);
      __syncthreads();
    }
    if (it + 1 < NH * 9) {
      const int h2 = (it + 1) / 9, tap2 = (it + 1) % 9;
      const int kg = tap2 * NKG + h2 * 4 + quad;
#pragma unroll
      for (int nf = 0; nf < NF; ++nf)
        bnxt[nf] = *(const short8*)(bp +
            ((size_t)kg * COUT + nwb + nf * 16 + l16) * 8);
    }
#pragma unroll
    for (int mf = 0; mf < MF; ++mf) {
      const int pi = (mw * MF + mf) * STRIDE + kh;
      const int slot = (STRIDE == 2) ? (l16 + (kw >> 1) + (kw & 1) * HALF)
                                     : (l16 + kw);
      const short8 a =
          *(const short8*)(&patch[((quad * PH + pi) * PWS + slot) * 8]);
#pragma unroll
      for (int nf = 0; nf < NF; ++nf)
        acc[mf][nf] = __builtin_amdgcn_mfma_f32_16x16x32_bf16(
            a, bcur[nf], acc[mf][nf], 0, 0, 0);
    }
#pragma unroll
    for (int nf = 0; nf < NF; ++nf) bcur[nf] = bnxt[nf];
  }

  // ---- epilogue
  float sc[NF], bs[NF];
#pragma unroll
  for (int nf = 0; nf < NF; ++nf) {
    sc[nf] = scale[nwb + nf * 16 + l16];
    bs[nf] = bias[nwb + nf * 16 + l16];
  }
  if (POOL) {
    float psum[NF];
#pragma unroll
    for (int nf = 0; nf < NF; ++nf) psum[nf] = 0.f;
#pragma unroll
    for (int mf = 0; mf < MF; ++mf)
#pragma unroll
      for (int r = 0; r < 4; ++r) {
        const int ow = ow0 + quad * 4 + r;
        if ((OW % TOW == 0) || ow < OW) {
#pragma unroll
          for (int nf = 0; nf < NF; ++nf)
            psum[nf] += fmaxf(acc[mf][nf][r] * sc[nf] + bs[nf], 0.f);
        }
      }
#pragma unroll
    for (int nf = 0; nf < NF; ++nf) {
      psum[nf] += __shfl_xor(psum[nf], 16);
      psum[nf] += __shfl_xor(psum[nf], 32);
    }
    if (quad == 0) {
#pragma unroll
      for (int nf = 0; nf < NF; ++nf)
        atomicAdd(&pooled[(size_t)img * COUT + nwb + nf * 16 + l16], psum[nf]);
    }
  } else {
#pragma unroll
    for (int mf = 0; mf < MF; ++mf) {
      const int oh = oh0 + mw * MF + mf;
#pragma unroll
      for (int r = 0; r < 4; ++r) {
        const int ow = ow0 + quad * 4 + r;
        if ((OW % TOW == 0) || ow < OW) {
          const size_t base = (((size_t)img * OH + oh) * OW + ow) * COUT + nwb;
#pragma unroll
          for (int nf = 0; nf < NF; ++nf) {
            const float vv = fmaxf(acc[mf][nf][r] * sc[nf] + bs[nf], 0.f);
            yout[base + nf * 16 + l16] = f2bf(vv);
          }
        }
      }
    }
  }
}

// ---------------------------------------------------------------- linear
// pooled holds SUMS over 3136 pixels; divide here.
__global__ void linear_kernel(const float* __restrict__ pooled,
                              const float* __restrict__ ql,
                              const float* __restrict__ bl,
                              float* __restrict__ out) {
  const int idx = blockIdx.x * blockDim.x + threadIdx.x;
  if (idx >= 64 * 10) return;
  const int n = idx / 10, o = idx % 10;
  const float* p = pooled + (size_t)n * 128;
  const float* w = ql + (size_t)o * 128;
  float s = 0.f;
#pragma unroll 4
  for (int c = 0; c < 128; ++c) s += p[c] * w[c];
  out[idx] = s * (1.f / 3136.f) + bl[o];
}

// ---------------------------------------------------------------- launch
extern "C" void kernel_launch(void* const* d_in, const int* in_sizes, int n_in,
                              void* d_out, int out_size, void* d_ws,
                              size_t ws_size, hipStream_t stream) {
  const float* x  = (const float*)d_in[0];
  const float* w1 = (const float*)d_in[1];
  const float* g1 = (const float*)d_in[2];
  const float* b1 = (const float*)d_in[3];
  const float* m1 = (const float*)d_in[4];
  const float* v1 = (const float*)d_in[5];
  const float* w2 = (const float*)d_in[6];
  const float* g2 = (const float*)d_in[7];
  const float* b2 = (const float*)d_in[8];
  const float* m2 = (const float*)d_in[9];
  const float* v2 = (const float*)d_in[10];
  const float* w3 = (const float*)d_in[11];
  const float* g3 = (const float*)d_in[12];
  const float* b3 = (const float*)d_in[13];
  const float* m3 = (const float*)d_in[14];
  const float* v3 = (const float*)d_in[15];
  const float* wl = (const float*)d_in[16];
  const float* bl = (const float*)d_in[17];
  float* out = (float*)d_out;

  // ---- workspace layout ----
  float* Wf = (float*)d_ws;
  float* red = Wf;                // 16 (4 tensors x {sum, cnt, asum, pad})
  float* pooled = red + 16;       // 8192 (zeroed with red in one memset)
  float* q1t = pooled + 8192;     // 864 (tap-major conv1 signs)
  float* ql = q1t + 864;          // 1280
  float* s1 = ql + 1280;  float* bb1 = s1 + 32;
  float* s2 = bb1 + 32;   float* bb2 = s2 + 64;
  float* s3 = bb2 + 64;   float* bb3 = s3 + 128;
  unsigned short* Us = (unsigned short*)(bb3 + 128);
  unsigned short* bp2 = Us;                 // 288*64   = 18432
  unsigned short* bp3 = bp2 + 18432;        // 576*128  = 73728
  unsigned short* act1 = bp3 + 73728;       // 64*12544*32 = 25690112
  unsigned short* act2 = act1 + 25690112;   // 64*12544*64 = 51380224
  // total ~155 MB < ws_size

  // ---- ternarize (grid-parallel, 3 phases over all 4 tensors) ----
  hipMemsetAsync(red, 0, (16 + 8192) * sizeof(float), stream);
  tern_phase1<<<dim3(288, 4), 256, 0, stream>>>(w1, w2, w3, wl, 864, 18432,
                                                73728, 1280, red);
  tern_phase2<<<dim3(288, 4), 256, 0, stream>>>(w1, w2, w3, wl, 864, 18432,
                                                73728, 1280, red);
  tern_phase3<<<5, 256, 0, stream>>>(wl, 1280, ql, red);

  bnfold_all<<<1, 256, 0, stream>>>(g1, b1, m1, v1, g2, b2, m2, v2, g3, b3,
                                    m3, v3, s1, bb1, s2, bb2, s3, bb3, red);
  pack_w1<<<4, 256, 0, stream>>>(w1, red, q1t);
  pack_weights<32, 64><<<72, 256, 0, stream>>>(w2, red + 4, bp2);
  pack_weights<64, 128><<<288, 256, 0, stream>>>(w3, red + 8, bp3);

  // ---- network ----
  conv1_v2<<<dim3(56, 64), 256, 0, stream>>>(x, q1t, s1, bb1, act1);
  conv_halo2<32, 64, 1, 112, 112, 112, 112, 4, 0>
      <<<dim3(98, 1, 64), 256, 0, stream>>>(act1, bp2, s2, bb2, act2, nullptr);
  conv_halo2<64, 128, 2, 112, 112, 56, 56, 2, 1>
      <<<dim3(28, 1, 64), 256, 0, stream>>>(act2, bp3, s3, bb3, nullptr,
                                            pooled);
  linear_kernel<<<3, 256, 0, stream>>>(pooled, ql, bl, out);
}